// Round 1
// baseline (16104.141 us; speedup 1.0000x reference)
//
#include <hip/hip_runtime.h>
#include <hip/hip_bf16.h>

#define BB 2
#define HH 192
#define WIMG 192
#define CC 192
#define NHEADS 6
#define HD 32
#define NTOK (HH*WIMG)        // 36864 tokens per image
#define NWX 24                // windows per axis
#define NWIN 576
#define BWIN (BB*NWIN)        // 1152
#define MLPH 768
#define EPS_ 1e-5f

// region id for the shifted-window attention mask (rolled-frame coords)
__device__ __forceinline__ int region_id(int wi, int wj, int ty, int tx) {
    int rh = (wi < NWX-1) ? 0 : ((ty < 4) ? 1 : 2);
    int rw = (wj < NWX-1) ? 0 : ((tx < 4) ? 1 : 2);
    return rh*3 + rw;
}

__device__ __forceinline__ float gelu_exact(float x) {
    return 0.5f * x * (1.0f + erff(x * 0.70710678118654752f));
}

// ---------------- K1: LayerNorm1 -> bf16 ----------------
__global__ __launch_bounds__(256) void ln1_kernel(
    const float* __restrict__ xl, const float* __restrict__ xr,
    const float* __restrict__ g, const float* __restrict__ bta,
    __hip_bfloat16* __restrict__ xl_ln, __hip_bfloat16* __restrict__ xr_ln)
{
    int token = blockIdx.x*4 + (threadIdx.x >> 6);
    int lane = threadIdx.x & 63;
    const float* src;
    __hip_bfloat16* dst;
    if (token < BB*NTOK) { src = xl + (size_t)token*CC; dst = xl_ln + (size_t)token*CC; }
    else { int t2 = token - BB*NTOK; src = xr + (size_t)t2*CC; dst = xr_ln + (size_t)t2*CC; }
    float v0 = src[lane], v1 = src[lane+64], v2 = src[lane+128];
    float s = v0+v1+v2;
    #pragma unroll
    for (int m = 32; m; m >>= 1) s += __shfl_xor(s, m, 64);
    float mu = s * (1.0f/CC);
    float d0 = v0-mu, d1 = v1-mu, d2 = v2-mu;
    float q = d0*d0 + d1*d1 + d2*d2;
    #pragma unroll
    for (int m = 32; m; m >>= 1) q += __shfl_xor(q, m, 64);
    float inv = rsqrtf(q*(1.0f/CC) + EPS_);
    dst[lane]     = __float2bfloat16(d0*inv*g[lane]     + bta[lane]);
    dst[lane+64]  = __float2bfloat16(d1*inv*g[lane+64]  + bta[lane+64]);
    dst[lane+128] = __float2bfloat16(d2*inv*g[lane+128] + bta[lane+128]);
}

// ---------------- K2/K3: windowed cross attention ----------------
// One block per (b, window). side 0: q from xq_src direct, kv gathered with
// r2l = int(max(j+0.5-d,0)); writes probs + o.  side 1: gather l2r =
// int(min(j+0.5+d,191)); reads probs(a_r2l), writes o + m_l + m_r.
// LDS layout (floats):
//  xq   @ 0      : 64*192
//  xkv  @ 12288  : 64*192
//  qbuf @ 24576  : 64*32
//  kbuf @ 26624  : 64*33 (padded; aliased as obuf after S is built)
//  vbuf @ 28736  : 64*32
//  STb  @ 30784  : 64*65  [key][query] padded
//  ArT  @ 34944  : 64*65  [key][query] padded
// total 39104 floats = 156416 B (dynamic LDS)
__global__ __launch_bounds__(256) void attn_kernel(
    const __hip_bfloat16* __restrict__ xq_src,
    const __hip_bfloat16* __restrict__ xkv_src,
    const float* __restrict__ disp,
    const float* __restrict__ q_w, const float* __restrict__ q_b,
    const float* __restrict__ kv_w, const float* __restrict__ kv_b,
    const float* __restrict__ bias_table,
    __hip_bfloat16* __restrict__ probs_out,
    const __hip_bfloat16* __restrict__ probs_in,
    float* __restrict__ o_out,
    float* __restrict__ m_l_out, float* __restrict__ m_r_out,
    int side)
{
    extern __shared__ float smem[];
    float* xq   = smem;
    float* xkv  = smem + 12288;
    float* qbuf = smem + 24576;
    float* kbuf = smem + 26624;
    float* vbuf = smem + 28736;
    float* STb  = smem + 30784;
    float* ArT  = smem + 34944;

    const int tid  = threadIdx.x;
    const int widx = blockIdx.x;
    const int b    = widx / NWIN;
    const int win  = widx % NWIN;
    const int wi   = win / NWX, wj = win % NWX;

    // -------- gather window tokens (shift + epipolar select folded in) -----
    for (int f = tid; f < 64*192; f += 256) {
        int p = f / 192, c = f - p*192;
        int rh = wi*8 + (p >> 3), rw = wj*8 + (p & 7);
        int i = rh + 4; if (i >= HH) i -= HH;
        int j = rw + 4; if (j >= WIMG) j -= WIMG;
        size_t row = (size_t)b*NTOK + i*WIMG + j;
        xq[f] = __bfloat162float(xq_src[row*CC + c]);
        float d = disp[((size_t)b*HH + i)*WIMG + j];
        int jj;
        if (side == 0) { float pos = (float)j + 0.5f - d; pos = fmaxf(pos, 0.0f); jj = (int)pos; }
        else           { float pos = (float)j + 0.5f + d; pos = fminf(pos, 191.0f); jj = (int)pos; }
        xkv[p*192 + c] = __bfloat162float(xkv_src[((size_t)b*NTOK + i*WIMG + jj)*CC + c]);
    }
    __syncthreads();

    const float scale = 0.17677669529663687f; // 32^-0.5

    for (int h = 0; h < NHEADS; ++h) {
        // ---- q projection for this head: 32 cols x 8 row-groups = 256 slots
        {
            int col = tid & 31, pg = tid >> 5;
            float acc[8];
            float qb = q_b[h*HD + col];
            #pragma unroll
            for (int r = 0; r < 8; ++r) acc[r] = qb;
            for (int k = 0; k < CC; ++k) {
                float w = q_w[k*CC + h*HD + col];
                #pragma unroll
                for (int r = 0; r < 8; ++r) acc[r] += xq[(pg*8+r)*192 + k] * w;
            }
            #pragma unroll
            for (int r = 0; r < 8; ++r) qbuf[(pg*8+r)*32 + col] = acc[r] * scale;
        }
        // ---- k,v projections: 64 col-slots (32 k + 32 v) x 8 row-groups
        for (int it = 0; it < 2; ++it) {
            int slot = tid + it*256;
            int cd = slot & 63, pg = slot >> 6;
            int col = (cd < 32) ? (h*HD + cd) : (CC + h*HD + (cd - 32));
            float acc[8];
            float kb = kv_b[col];
            #pragma unroll
            for (int r = 0; r < 8; ++r) acc[r] = kb;
            for (int k = 0; k < CC; ++k) {
                float w = kv_w[k*(2*CC) + col];
                #pragma unroll
                for (int r = 0; r < 8; ++r) acc[r] += xkv[(pg*8+r)*192 + k] * w;
            }
            if (cd < 32) {
                #pragma unroll
                for (int r = 0; r < 8; ++r) kbuf[(pg*8+r)*33 + cd] = acc[r];
            } else {
                #pragma unroll
                for (int r = 0; r < 8; ++r) vbuf[(pg*8+r)*32 + (cd-32)] = acc[r];
            }
        }
        __syncthreads();

        // ---- S = q k^T * scale + rel_bias + mask ; stored [key][query] pad65
        {
            int ki = tid & 63, g = tid >> 6;   // wave g handles queries g*16..+15
            float acc[16];
            #pragma unroll
            for (int r = 0; r < 16; ++r) acc[r] = 0.0f;
            for (int d = 0; d < HD; ++d) {
                float kv_ = kbuf[ki*33 + d];
                #pragma unroll
                for (int r = 0; r < 16; ++r) acc[r] += qbuf[(g*16+r)*32 + d] * kv_;
            }
            int ky = ki >> 3, kx = ki & 7;
            int regk = region_id(wi, wj, ky, kx);
            #pragma unroll
            for (int r = 0; r < 16; ++r) {
                int qi = g*16 + r;
                int qy = qi >> 3, qx = qi & 7;
                int ridx = (qy - ky + 7)*15 + (qx - kx + 7);
                float bias = bias_table[ridx*NHEADS + h];
                int regq = region_id(wi, wj, qy, qx);
                float msk = (regq != regk) ? -100.0f : 0.0f;
                STb[ki*65 + qi] = acc[r] + bias + msk;
            }
        }
        __syncthreads();

        // ---- softmax per query row (one lane per query)
        if (tid < 64) {
            float mx = -1e30f;
            for (int k = 0; k < 64; ++k) mx = fmaxf(mx, STb[k*65 + tid]);
            float s = 0.0f;
            for (int k = 0; k < 64; ++k) {
                float e = __expf(STb[k*65 + tid] - mx);
                STb[k*65 + tid] = e;
                s += e;
            }
            float inv = 1.0f / s;
            for (int k = 0; k < 64; ++k) STb[k*65 + tid] *= inv;
        }
        __syncthreads();

        if (side == 0) {
            // store probs a_r2l[widx][h][q][k] (bf16)
            for (int f = tid; f < 4096; f += 256) {
                int q = f >> 6, k = f & 63;
                probs_out[((size_t)widx*NHEADS + h)*4096 + f] = __float2bfloat16(STb[k*65 + q]);
            }
        } else {
            // load a_r2l into ArT[key][query]
            for (int f = tid; f < 4096; f += 256) {
                int q = f >> 6, k = f & 63;
                ArT[k*65 + q] = __bfloat162float(probs_in[((size_t)widx*NHEADS + h)*4096 + f]);
            }
            __syncthreads();
            // m_l[i] = sum_k relax(a_r2l)[i,k] * a_l2r[k,i]
            // m_r[i] = sum_k relax(a_l2r)[i,k] * a_r2l[k,i]
            if (tid < 64) {
                int i = tid;
                float accl = 0.0f, accr = 0.0f;
                for (int k = 0; k < 64; ++k) {
                    float relax_r = 0.0f, relax_l = 0.0f;
                    #pragma unroll
                    for (int s = -2; s <= 2; ++s) {
                        int is = i + s;
                        if (is >= 0 && is < 64) {
                            relax_r += ArT[k*65 + is];
                            relax_l += STb[k*65 + is];
                        }
                    }
                    accl += relax_r * STb[i*65 + k];
                    accr += relax_l * ArT[i*65 + k];
                }
                m_l_out[((size_t)widx*NHEADS + h)*64 + i] = tanhf(5.0f * accl);
                m_r_out[((size_t)widx*NHEADS + h)*64 + i] = tanhf(5.0f * accr);
            }
        }

        // ---- PV: o[p][d] = sum_k P[p][k] * v[k][d]; obuf aliases kbuf
        {
            int p = tid & 63, wv = tid >> 6;
            float acc[8];
            #pragma unroll
            for (int dd = 0; dd < 8; ++dd) acc[dd] = 0.0f;
            for (int k = 0; k < 64; ++k) {
                float pr = STb[k*65 + p];
                #pragma unroll
                for (int dd = 0; dd < 8; ++dd) acc[dd] += pr * vbuf[k*32 + wv*8 + dd];
            }
            float* obuf = kbuf;
            #pragma unroll
            for (int dd = 0; dd < 8; ++dd) obuf[p*33 + wv*8 + dd] = acc[dd];
        }
        __syncthreads();
        // coalesced o write: o[widx][p][h*32+d]
        for (int f = tid; f < 2048; f += 256) {
            int p = f >> 5, d = f & 31;
            o_out[((size_t)widx*64 + p)*CC + h*HD + d] = kbuf[p*33 + d];
        }
        __syncthreads();
    }
}

// ---------------- K4: proj + fuse + window reverse + residual ----------------
__global__ __launch_bounds__(256) void fuse_proj_kernel(
    const float* __restrict__ o_in,
    const __hip_bfloat16* __restrict__ ln_src,
    const float* __restrict__ m_in,
    const float* __restrict__ proj_w, const float* __restrict__ proj_b,
    const float* __restrict__ x_orig,
    float* __restrict__ out_half)
{
    __shared__ float otile[12288];
    const int widx = blockIdx.x;
    const int b = widx / NWIN, win = widx % NWIN;
    const int wi = win / NWX, wj = win % NWX;

    for (int f = threadIdx.x; f < 12288; f += 256)
        otile[f] = o_in[(size_t)widx*12288 + f];
    __syncthreads();

    for (int it = 0; it < 6; ++it) {
        int slot = threadIdx.x + it*256;
        int o = slot % CC, pg = slot / CC;
        float acc[8];
        float pb = proj_b[o];
        #pragma unroll
        for (int r = 0; r < 8; ++r) acc[r] = pb;
        for (int k = 0; k < CC; ++k) {
            float w = proj_w[k*CC + o];
            #pragma unroll
            for (int r = 0; r < 8; ++r) acc[r] += otile[(pg*8+r)*192 + k] * w;
        }
        int head = o >> 5;
        #pragma unroll
        for (int r = 0; r < 8; ++r) {
            int p = pg*8 + r;
            int rh = wi*8 + (p >> 3), rw = wj*8 + (p & 7);
            int i = rh + 4; if (i >= HH) i -= HH;
            int j = rw + 4; if (j >= WIMG) j -= WIMG;
            size_t row = (size_t)b*NTOK + i*WIMG + j;
            float m = m_in[((size_t)widx*NHEADS + head)*64 + p];
            float xw = __bfloat162float(ln_src[row*CC + o]);
            float fused = xw + (acc[r] - xw) * m;
            out_half[row*CC + o] = x_orig[row*CC + o] + fused;
        }
    }
}

// ---------------- K5: fused MLP (LN2 + fc1 + GELU + fc2 + residual), in-place
// LDS: xt 64*192 f32 (12288) + hbuf 64*128 f32 (8192) = 20480 floats (80KB)
__global__ __launch_bounds__(256) void mlp_kernel(
    float* __restrict__ out,
    const float* __restrict__ g2, const float* __restrict__ b2,
    const float* __restrict__ fc1_w, const float* __restrict__ fc1_b,
    const float* __restrict__ fc2_w, const float* __restrict__ fc2_b)
{
    extern __shared__ float smem[];
    float* xt   = smem;          // 64 x 192
    float* hbuf = smem + 12288;  // 64 x 128

    const int tid = threadIdx.x;
    const size_t base = (size_t)blockIdx.x * 64 * CC;

    for (int f = tid; f < 12288; f += 256) xt[f] = out[base + f];
    __syncthreads();

    // LN2 (4 lanes per token)
    {
        int p = tid >> 2, q4 = tid & 3;
        float s = 0.0f;
        for (int i = 0; i < 48; ++i) s += xt[p*192 + q4*48 + i];
        s += __shfl_xor(s, 1, 64); s += __shfl_xor(s, 2, 64);
        float mu = s * (1.0f/CC);
        float v = 0.0f;
        for (int i = 0; i < 48; ++i) { float d = xt[p*192 + q4*48 + i] - mu; v += d*d; }
        v += __shfl_xor(v, 1, 64); v += __shfl_xor(v, 2, 64);
        float inv = rsqrtf(v*(1.0f/CC) + EPS_);
        for (int i = 0; i < 48; ++i) {
            int c = q4*48 + i;
            xt[p*192 + c] = (xt[p*192 + c] - mu)*inv*g2[c] + b2[c];
        }
    }
    __syncthreads();

    float racc[6][8];
    #pragma unroll
    for (int s = 0; s < 6; ++s)
        #pragma unroll
        for (int r = 0; r < 8; ++r) racc[s][r] = 0.0f;

    for (int ch = 0; ch < 6; ++ch) {
        // fc1 chunk + GELU -> hbuf
        for (int it = 0; it < 4; ++it) {
            int slot = tid + it*256;
            int col = slot & 127, pg = slot >> 7;
            float acc[8];
            float fb = fc1_b[ch*128 + col];
            #pragma unroll
            for (int r = 0; r < 8; ++r) acc[r] = fb;
            for (int k = 0; k < CC; ++k) {
                float w = fc1_w[k*MLPH + ch*128 + col];
                #pragma unroll
                for (int r = 0; r < 8; ++r) acc[r] += xt[(pg*8+r)*192 + k] * w;
            }
            #pragma unroll
            for (int r = 0; r < 8; ++r) hbuf[(pg*8+r)*128 + col] = gelu_exact(acc[r]);
        }
        __syncthreads();
        // fc2 chunk accumulate into registers
        #pragma unroll
        for (int s = 0; s < 6; ++s) {
            int slot = tid + s*256;
            int o = slot % CC, pg = slot / CC;
            float acc[8];
            #pragma unroll
            for (int r = 0; r < 8; ++r) acc[r] = 0.0f;
            for (int k = 0; k < 128; ++k) {
                float w = fc2_w[(size_t)(ch*128 + k)*CC + o];
                #pragma unroll
                for (int r = 0; r < 8; ++r) acc[r] += hbuf[(pg*8+r)*128 + k] * w;
            }
            #pragma unroll
            for (int r = 0; r < 8; ++r) racc[s][r] += acc[r];
        }
        __syncthreads();
    }

    // residual + bias + store (in-place safe: each element touched by owner only)
    #pragma unroll
    for (int s = 0; s < 6; ++s) {
        int slot = tid + s*256;
        int o = slot % CC, pg = slot / CC;
        float fb = fc2_b[o];
        #pragma unroll
        for (int r = 0; r < 8; ++r) {
            size_t idx = base + (size_t)(pg*8 + r)*CC + o;
            out[idx] = out[idx] + racc[s][r] + fb;
        }
    }
}

// ---------------- launch ----------------
extern "C" void kernel_launch(void* const* d_in, const int* in_sizes, int n_in,
                              void* d_out, int out_size, void* d_ws, size_t ws_size,
                              hipStream_t stream)
{
    (void)in_sizes; (void)n_in; (void)out_size; (void)ws_size;
    const float* x_left  = (const float*)d_in[0];
    const float* x_right = (const float*)d_in[1];
    const float* d_left  = (const float*)d_in[2];
    const float* d_right = (const float*)d_in[3];
    const float* n1g = (const float*)d_in[4];
    const float* n1b = (const float*)d_in[5];
    const float* q_w = (const float*)d_in[6];
    const float* q_b = (const float*)d_in[7];
    const float* kv_w = (const float*)d_in[8];
    const float* kv_b = (const float*)d_in[9];
    const float* proj_w = (const float*)d_in[10];
    const float* proj_b = (const float*)d_in[11];
    const float* bias_table = (const float*)d_in[12];
    const float* n2g = (const float*)d_in[13];
    const float* n2b = (const float*)d_in[14];
    const float* fc1_w = (const float*)d_in[15];
    const float* fc1_b = (const float*)d_in[16];
    const float* fc2_w = (const float*)d_in[17];
    const float* fc2_b = (const float*)d_in[18];
    float* out = (float*)d_out;

    char* ws = (char*)d_ws;
    __hip_bfloat16* xl_ln = (__hip_bfloat16*)(ws);
    __hip_bfloat16* xr_ln = (__hip_bfloat16*)(ws + 28311552);
    __hip_bfloat16* probs = (__hip_bfloat16*)(ws + 56623104);
    float* o_l = (float*)(ws + 113246208);
    float* o_r = (float*)(ws + 169869312);
    float* m_l = (float*)(ws + 226492416);
    float* m_r = (float*)(ws + 228261888);

    ln1_kernel<<<(2*BB*NTOK)/4, 256, 0, stream>>>(x_left, x_right, n1g, n1b, xl_ln, xr_ln);

    const size_t attn_lds = 39104u * sizeof(float);
    attn_kernel<<<BWIN, 256, attn_lds, stream>>>(
        xl_ln, xr_ln, d_left, q_w, q_b, kv_w, kv_b, bias_table,
        probs, nullptr, o_l, nullptr, nullptr, 0);
    attn_kernel<<<BWIN, 256, attn_lds, stream>>>(
        xr_ln, xl_ln, d_right, q_w, q_b, kv_w, kv_b, bias_table,
        nullptr, probs, o_r, m_l, m_r, 1);

    fuse_proj_kernel<<<BWIN, 256, 0, stream>>>(o_l, xl_ln, m_l, proj_w, proj_b, x_left, out);
    fuse_proj_kernel<<<BWIN, 256, 0, stream>>>(o_r, xr_ln, m_r, proj_w, proj_b, x_right,
                                               out + (size_t)BB*NTOK*CC);

    mlp_kernel<<<(2*BB*NTOK)/64, 256, 20480u*sizeof(float), stream>>>(
        out, n2g, n2b, fc1_w, fc1_b, fc2_w, fc2_b);
}

// Round 2
// 9093.919 us; speedup vs baseline: 1.7709x; 1.7709x over previous
//
#include <hip/hip_runtime.h>
#include <hip/hip_bf16.h>

#define BB 2
#define HH 192
#define WIMG 192
#define CC 192
#define NHEADS 6
#define HD 32
#define NTOK (HH*WIMG)        // 36864 tokens per image
#define NWX 24                // windows per axis
#define NWIN 576
#define BWIN (BB*NWIN)        // 1152
#define MLPH 768
#define EPS_ 1e-5f

typedef __attribute__((ext_vector_type(8))) short bf16x8;
typedef __attribute__((ext_vector_type(4))) float f32x4;

// region id for the shifted-window attention mask (rolled-frame coords)
__device__ __forceinline__ int region_id(int wi, int wj, int ty, int tx) {
    int rh = (wi < NWX-1) ? 0 : ((ty < 4) ? 1 : 2);
    int rw = (wj < NWX-1) ? 0 : ((tx < 4) ? 1 : 2);
    return rh*3 + rw;
}

__device__ __forceinline__ float gelu_exact(float x) {
    return 0.5f * x * (1.0f + erff(x * 0.70710678118654752f));
}

// ---------------- K1: LayerNorm1 -> bf16 ----------------
__global__ __launch_bounds__(256) void ln1_kernel(
    const float* __restrict__ xl, const float* __restrict__ xr,
    const float* __restrict__ g, const float* __restrict__ bta,
    __hip_bfloat16* __restrict__ xl_ln, __hip_bfloat16* __restrict__ xr_ln)
{
    int token = blockIdx.x*4 + (threadIdx.x >> 6);
    int lane = threadIdx.x & 63;
    const float* src;
    __hip_bfloat16* dst;
    if (token < BB*NTOK) { src = xl + (size_t)token*CC; dst = xl_ln + (size_t)token*CC; }
    else { int t2 = token - BB*NTOK; src = xr + (size_t)t2*CC; dst = xr_ln + (size_t)t2*CC; }
    float v0 = src[lane], v1 = src[lane+64], v2 = src[lane+128];
    float s = v0+v1+v2;
    #pragma unroll
    for (int m = 32; m; m >>= 1) s += __shfl_xor(s, m, 64);
    float mu = s * (1.0f/CC);
    float d0 = v0-mu, d1 = v1-mu, d2 = v2-mu;
    float q = d0*d0 + d1*d1 + d2*d2;
    #pragma unroll
    for (int m = 32; m; m >>= 1) q += __shfl_xor(q, m, 64);
    float inv = rsqrtf(q*(1.0f/CC) + EPS_);
    dst[lane]     = __float2bfloat16(d0*inv*g[lane]     + bta[lane]);
    dst[lane+64]  = __float2bfloat16(d1*inv*g[lane+64]  + bta[lane+64]);
    dst[lane+128] = __float2bfloat16(d2*inv*g[lane+128] + bta[lane+128]);
}

// ---------------- K2/K3: windowed cross attention ----------------
__global__ __launch_bounds__(256) void attn_kernel(
    const __hip_bfloat16* __restrict__ xq_src,
    const __hip_bfloat16* __restrict__ xkv_src,
    const float* __restrict__ disp,
    const float* __restrict__ q_w, const float* __restrict__ q_b,
    const float* __restrict__ kv_w, const float* __restrict__ kv_b,
    const float* __restrict__ bias_table,
    __hip_bfloat16* __restrict__ probs_out,
    const __hip_bfloat16* __restrict__ probs_in,
    float* __restrict__ o_out,
    float* __restrict__ m_l_out, float* __restrict__ m_r_out,
    int side)
{
    extern __shared__ float smem[];
    float* xq   = smem;
    float* xkv  = smem + 12288;
    float* qbuf = smem + 24576;
    float* kbuf = smem + 26624;
    float* vbuf = smem + 28736;
    float* STb  = smem + 30784;
    float* ArT  = smem + 34944;

    const int tid  = threadIdx.x;
    const int widx = blockIdx.x;
    const int b    = widx / NWIN;
    const int win  = widx % NWIN;
    const int wi   = win / NWX, wj = win % NWX;

    for (int f = tid; f < 64*192; f += 256) {
        int p = f / 192, c = f - p*192;
        int rh = wi*8 + (p >> 3), rw = wj*8 + (p & 7);
        int i = rh + 4; if (i >= HH) i -= HH;
        int j = rw + 4; if (j >= WIMG) j -= WIMG;
        size_t row = (size_t)b*NTOK + i*WIMG + j;
        xq[f] = __bfloat162float(xq_src[row*CC + c]);
        float d = disp[((size_t)b*HH + i)*WIMG + j];
        int jj;
        if (side == 0) { float pos = (float)j + 0.5f - d; pos = fmaxf(pos, 0.0f); jj = (int)pos; }
        else           { float pos = (float)j + 0.5f + d; pos = fminf(pos, 191.0f); jj = (int)pos; }
        xkv[p*192 + c] = __bfloat162float(xkv_src[((size_t)b*NTOK + i*WIMG + jj)*CC + c]);
    }
    __syncthreads();

    const float scale = 0.17677669529663687f; // 32^-0.5

    for (int h = 0; h < NHEADS; ++h) {
        {
            int col = tid & 31, pg = tid >> 5;
            float acc[8];
            float qb = q_b[h*HD + col];
            #pragma unroll
            for (int r = 0; r < 8; ++r) acc[r] = qb;
            for (int k = 0; k < CC; ++k) {
                float w = q_w[k*CC + h*HD + col];
                #pragma unroll
                for (int r = 0; r < 8; ++r) acc[r] += xq[(pg*8+r)*192 + k] * w;
            }
            #pragma unroll
            for (int r = 0; r < 8; ++r) qbuf[(pg*8+r)*32 + col] = acc[r] * scale;
        }
        for (int it = 0; it < 2; ++it) {
            int slot = tid + it*256;
            int cd = slot & 63, pg = slot >> 6;
            int col = (cd < 32) ? (h*HD + cd) : (CC + h*HD + (cd - 32));
            float acc[8];
            float kb = kv_b[col];
            #pragma unroll
            for (int r = 0; r < 8; ++r) acc[r] = kb;
            for (int k = 0; k < CC; ++k) {
                float w = kv_w[k*(2*CC) + col];
                #pragma unroll
                for (int r = 0; r < 8; ++r) acc[r] += xkv[(pg*8+r)*192 + k] * w;
            }
            if (cd < 32) {
                #pragma unroll
                for (int r = 0; r < 8; ++r) kbuf[(pg*8+r)*33 + cd] = acc[r];
            } else {
                #pragma unroll
                for (int r = 0; r < 8; ++r) vbuf[(pg*8+r)*32 + (cd-32)] = acc[r];
            }
        }
        __syncthreads();

        {
            int ki = tid & 63, g = tid >> 6;
            float acc[16];
            #pragma unroll
            for (int r = 0; r < 16; ++r) acc[r] = 0.0f;
            for (int d = 0; d < HD; ++d) {
                float kv_ = kbuf[ki*33 + d];
                #pragma unroll
                for (int r = 0; r < 16; ++r) acc[r] += qbuf[(g*16+r)*32 + d] * kv_;
            }
            int ky = ki >> 3, kx = ki & 7;
            int regk = region_id(wi, wj, ky, kx);
            #pragma unroll
            for (int r = 0; r < 16; ++r) {
                int qi = g*16 + r;
                int qy = qi >> 3, qx = qi & 7;
                int ridx = (qy - ky + 7)*15 + (qx - kx + 7);
                float bias = bias_table[ridx*NHEADS + h];
                int regq = region_id(wi, wj, qy, qx);
                float msk = (regq != regk) ? -100.0f : 0.0f;
                STb[ki*65 + qi] = acc[r] + bias + msk;
            }
        }
        __syncthreads();

        if (tid < 64) {
            float mx = -1e30f;
            for (int k = 0; k < 64; ++k) mx = fmaxf(mx, STb[k*65 + tid]);
            float s = 0.0f;
            for (int k = 0; k < 64; ++k) {
                float e = __expf(STb[k*65 + tid] - mx);
                STb[k*65 + tid] = e;
                s += e;
            }
            float inv = 1.0f / s;
            for (int k = 0; k < 64; ++k) STb[k*65 + tid] *= inv;
        }
        __syncthreads();

        if (side == 0) {
            for (int f = tid; f < 4096; f += 256) {
                int q = f >> 6, k = f & 63;
                probs_out[((size_t)widx*NHEADS + h)*4096 + f] = __float2bfloat16(STb[k*65 + q]);
            }
        } else {
            for (int f = tid; f < 4096; f += 256) {
                int q = f >> 6, k = f & 63;
                ArT[k*65 + q] = __bfloat162float(probs_in[((size_t)widx*NHEADS + h)*4096 + f]);
            }
            __syncthreads();
            if (tid < 64) {
                int i = tid;
                float accl = 0.0f, accr = 0.0f;
                for (int k = 0; k < 64; ++k) {
                    float relax_r = 0.0f, relax_l = 0.0f;
                    #pragma unroll
                    for (int s = -2; s <= 2; ++s) {
                        int is = i + s;
                        if (is >= 0 && is < 64) {
                            relax_r += ArT[k*65 + is];
                            relax_l += STb[k*65 + is];
                        }
                    }
                    accl += relax_r * STb[i*65 + k];
                    accr += relax_l * ArT[i*65 + k];
                }
                m_l_out[((size_t)widx*NHEADS + h)*64 + i] = tanhf(5.0f * accl);
                m_r_out[((size_t)widx*NHEADS + h)*64 + i] = tanhf(5.0f * accr);
            }
        }

        {
            int p = tid & 63, wv = tid >> 6;
            float acc[8];
            #pragma unroll
            for (int dd = 0; dd < 8; ++dd) acc[dd] = 0.0f;
            for (int k = 0; k < 64; ++k) {
                float pr = STb[k*65 + p];
                #pragma unroll
                for (int dd = 0; dd < 8; ++dd) acc[dd] += pr * vbuf[k*32 + wv*8 + dd];
            }
            float* obuf = kbuf;
            #pragma unroll
            for (int dd = 0; dd < 8; ++dd) obuf[p*33 + wv*8 + dd] = acc[dd];
        }
        __syncthreads();
        for (int f = tid; f < 2048; f += 256) {
            int p = f >> 5, d = f & 31;
            o_out[((size_t)widx*64 + p)*CC + h*HD + d] = kbuf[p*33 + d];
        }
        __syncthreads();
    }
}

// ---------------- K4: proj + fuse + window reverse + residual ----------------
__global__ __launch_bounds__(256) void fuse_proj_kernel(
    const float* __restrict__ o_in,
    const __hip_bfloat16* __restrict__ ln_src,
    const float* __restrict__ m_in,
    const float* __restrict__ proj_w, const float* __restrict__ proj_b,
    const float* __restrict__ x_orig,
    float* __restrict__ out_half)
{
    __shared__ float otile[12288];
    const int widx = blockIdx.x;
    const int b = widx / NWIN, win = widx % NWIN;
    const int wi = win / NWX, wj = win % NWX;

    for (int f = threadIdx.x; f < 12288; f += 256)
        otile[f] = o_in[(size_t)widx*12288 + f];
    __syncthreads();

    for (int it = 0; it < 6; ++it) {
        int slot = threadIdx.x + it*256;
        int o = slot % CC, pg = slot / CC;
        float acc[8];
        float pb = proj_b[o];
        #pragma unroll
        for (int r = 0; r < 8; ++r) acc[r] = pb;
        for (int k = 0; k < CC; ++k) {
            float w = proj_w[k*CC + o];
            #pragma unroll
            for (int r = 0; r < 8; ++r) acc[r] += otile[(pg*8+r)*192 + k] * w;
        }
        int head = o >> 5;
        #pragma unroll
        for (int r = 0; r < 8; ++r) {
            int p = pg*8 + r;
            int rh = wi*8 + (p >> 3), rw = wj*8 + (p & 7);
            int i = rh + 4; if (i >= HH) i -= HH;
            int j = rw + 4; if (j >= WIMG) j -= WIMG;
            size_t row = (size_t)b*NTOK + i*WIMG + j;
            float m = m_in[((size_t)widx*NHEADS + head)*64 + p];
            float xw = __bfloat162float(ln_src[row*CC + o]);
            float fused = xw + (acc[r] - xw) * m;
            out_half[row*CC + o] = x_orig[row*CC + o] + fused;
        }
    }
}

// ---------------- weight convert+transpose to bf16 ----------------
__global__ __launch_bounds__(256) void conv_weights_kernel(
    const float* __restrict__ fc1_w, const float* __restrict__ fc2_w,
    __hip_bfloat16* __restrict__ W1t, __hip_bfloat16* __restrict__ W2t)
{
    int idx = blockIdx.x*256 + threadIdx.x;
    if (idx < MLPH*CC) {
        int c = idx / CC, k = idx - c*CC;         // W1t[c][k] = fc1_w[k][c]
        W1t[idx] = __float2bfloat16(fc1_w[(size_t)k*MLPH + c]);
    } else {
        int j = idx - MLPH*CC;
        int c = j / MLPH, k = j - c*MLPH;          // W2t[c][k] = fc2_w[k][c]
        W2t[j] = __float2bfloat16(fc2_w[(size_t)k*CC + c]);
    }
}

// ---------------- K5: fused MLP via bf16 MFMA ----------------
// 64 tokens/block, 4 waves; wave w owns rows 16w..16w+15 (LDS wave-private:
// no __syncthreads in the main loop). LDS 34.8KB -> 4 blocks/CU.
__global__ __launch_bounds__(256) void mlp_mfma_kernel(
    float* __restrict__ out,
    const float* __restrict__ g2, const float* __restrict__ b2,
    const __hip_bfloat16* __restrict__ W1t, const float* __restrict__ fc1_b,
    const __hip_bfloat16* __restrict__ W2t, const float* __restrict__ fc2_b)
{
    __shared__ __hip_bfloat16 xt[64*200];   // pad 200: 2-way max on ds_read_b128
    __shared__ __hip_bfloat16 hbuf[64*72];  // pad 72
    const int tid  = threadIdx.x;
    const int lane = tid & 63;
    const int w    = tid >> 6;
    const size_t base = (size_t)blockIdx.x * 64 * CC;

    // LN2 -> bf16 xt (wave shuffle-reduce, one token at a time)
    for (int t = 0; t < 16; ++t) {
        int row = w*16 + t;
        const float* src = out + base + (size_t)row*CC;
        float v0 = src[lane], v1 = src[lane+64], v2 = src[lane+128];
        float s = v0+v1+v2;
        #pragma unroll
        for (int m = 32; m; m >>= 1) s += __shfl_xor(s, m, 64);
        float mu = s * (1.0f/CC);
        float d0 = v0-mu, d1 = v1-mu, d2 = v2-mu;
        float q = d0*d0 + d1*d1 + d2*d2;
        #pragma unroll
        for (int m = 32; m; m >>= 1) q += __shfl_xor(q, m, 64);
        float inv = rsqrtf(q*(1.0f/CC) + EPS_);
        xt[row*200 + lane]       = __float2bfloat16(d0*inv*g2[lane]      + b2[lane]);
        xt[row*200 + lane + 64]  = __float2bfloat16(d1*inv*g2[lane+64]   + b2[lane+64]);
        xt[row*200 + lane + 128] = __float2bfloat16(d2*inv*g2[lane+128]  + b2[lane+128]);
    }

    const int r16 = lane & 15;   // A row / B,C col within tile
    const int kg  = lane >> 4;   // k-group of 8
    const int w16 = w * 16;

    f32x4 acc2[12];
    #pragma unroll
    for (int i = 0; i < 12; ++i) acc2[i] = (f32x4){0.f,0.f,0.f,0.f};

    for (int cc = 0; cc < 12; ++cc) {
        // ---- fc1 chunk: hidden cols cc*64..+63
        f32x4 acc1[4];
        #pragma unroll
        for (int ct = 0; ct < 4; ++ct) {
            float bb = fc1_b[cc*64 + ct*16 + r16];
            acc1[ct] = (f32x4){bb,bb,bb,bb};
        }
        #pragma unroll
        for (int ks = 0; ks < 6; ++ks) {
            bf16x8 a = *reinterpret_cast<const bf16x8*>(&xt[(w16 + r16)*200 + ks*32 + kg*8]);
            #pragma unroll
            for (int ct = 0; ct < 4; ++ct) {
                bf16x8 bw = *reinterpret_cast<const bf16x8*>(
                    &W1t[(size_t)(cc*64 + ct*16 + r16)*CC + ks*32 + kg*8]);
                acc1[ct] = __builtin_amdgcn_mfma_f32_16x16x32_bf16(a, bw, acc1[ct], 0, 0, 0);
            }
        }
        // ---- GELU -> hbuf (C-frag: col=lane&15, row=(lane>>4)*4+r)
        #pragma unroll
        for (int ct = 0; ct < 4; ++ct)
            #pragma unroll
            for (int r = 0; r < 4; ++r)
                hbuf[(w16 + kg*4 + r)*72 + ct*16 + r16] =
                    __float2bfloat16(gelu_exact(acc1[ct][r]));
        // ---- fc2 chunk accumulate (K=64)
        #pragma unroll
        for (int ks = 0; ks < 2; ++ks) {
            bf16x8 a2 = *reinterpret_cast<const bf16x8*>(&hbuf[(w16 + r16)*72 + ks*32 + kg*8]);
            #pragma unroll
            for (int ct = 0; ct < 12; ++ct) {
                bf16x8 bw = *reinterpret_cast<const bf16x8*>(
                    &W2t[(size_t)(ct*16 + r16)*MLPH + cc*64 + ks*32 + kg*8]);
                acc2[ct] = __builtin_amdgcn_mfma_f32_16x16x32_bf16(a2, bw, acc2[ct], 0, 0, 0);
            }
        }
    }

    // ---- epilogue: out += mlp + fc2_b (RMW, each element owned by one lane)
    #pragma unroll
    for (int ct = 0; ct < 12; ++ct) {
        int col = ct*16 + r16;
        float bb = fc2_b[col];
        #pragma unroll
        for (int r = 0; r < 4; ++r) {
            size_t idx = base + (size_t)(w16 + kg*4 + r)*CC + col;
            out[idx] = out[idx] + acc2[ct][r] + bb;
        }
    }
}

// ---------------- launch ----------------
extern "C" void kernel_launch(void* const* d_in, const int* in_sizes, int n_in,
                              void* d_out, int out_size, void* d_ws, size_t ws_size,
                              hipStream_t stream)
{
    (void)in_sizes; (void)n_in; (void)out_size; (void)ws_size;
    const float* x_left  = (const float*)d_in[0];
    const float* x_right = (const float*)d_in[1];
    const float* d_left  = (const float*)d_in[2];
    const float* d_right = (const float*)d_in[3];
    const float* n1g = (const float*)d_in[4];
    const float* n1b = (const float*)d_in[5];
    const float* q_w = (const float*)d_in[6];
    const float* q_b = (const float*)d_in[7];
    const float* kv_w = (const float*)d_in[8];
    const float* kv_b = (const float*)d_in[9];
    const float* proj_w = (const float*)d_in[10];
    const float* proj_b = (const float*)d_in[11];
    const float* bias_table = (const float*)d_in[12];
    const float* n2g = (const float*)d_in[13];
    const float* n2b = (const float*)d_in[14];
    const float* fc1_w = (const float*)d_in[15];
    const float* fc1_b = (const float*)d_in[16];
    const float* fc2_w = (const float*)d_in[17];
    const float* fc2_b = (const float*)d_in[18];
    float* out = (float*)d_out;

    char* ws = (char*)d_ws;
    __hip_bfloat16* xl_ln = (__hip_bfloat16*)(ws);
    __hip_bfloat16* xr_ln = (__hip_bfloat16*)(ws + 28311552);
    __hip_bfloat16* probs = (__hip_bfloat16*)(ws + 56623104);
    float* o_l = (float*)(ws + 113246208);
    float* o_r = (float*)(ws + 169869312);
    float* m_l = (float*)(ws + 226492416);
    float* m_r = (float*)(ws + 228261888);
    // W1t/W2t reuse the probs region (dead after attn side 1)
    __hip_bfloat16* W1t = (__hip_bfloat16*)(ws + 56623104);
    __hip_bfloat16* W2t = (__hip_bfloat16*)(ws + 56623104 + 294912);

    ln1_kernel<<<(2*BB*NTOK)/4, 256, 0, stream>>>(x_left, x_right, n1g, n1b, xl_ln, xr_ln);

    const size_t attn_lds = 39104u * sizeof(float);
    attn_kernel<<<BWIN, 256, attn_lds, stream>>>(
        xl_ln, xr_ln, d_left, q_w, q_b, kv_w, kv_b, bias_table,
        probs, nullptr, o_l, nullptr, nullptr, 0);
    attn_kernel<<<BWIN, 256, attn_lds, stream>>>(
        xr_ln, xl_ln, d_right, q_w, q_b, kv_w, kv_b, bias_table,
        nullptr, probs, o_r, m_l, m_r, 1);

    // probs dead from here; convert MLP weights into that region
    conv_weights_kernel<<<(2*MLPH*CC)/256, 256, 0, stream>>>(fc1_w, fc2_w, W1t, W2t);

    fuse_proj_kernel<<<BWIN, 256, 0, stream>>>(o_l, xl_ln, m_l, proj_w, proj_b, x_left, out);
    fuse_proj_kernel<<<BWIN, 256, 0, stream>>>(o_r, xr_ln, m_r, proj_w, proj_b, x_right,
                                               out + (size_t)BB*NTOK*CC);

    mlp_mfma_kernel<<<(2*BB*NTOK)/64, 256, 0, stream>>>(
        out, n2g, n2b, W1t, fc1_b, W2t, fc2_b);
}

// Round 3
// 1473.453 us; speedup vs baseline: 10.9295x; 6.1718x over previous
//
#include <hip/hip_runtime.h>
#include <hip/hip_bf16.h>

#define BB 2
#define HH 192
#define WIMG 192
#define CC 192
#define NHEADS 6
#define HD 32
#define NTOK (HH*WIMG)        // 36864 tokens per image
#define NWX 24                // windows per axis
#define NWIN 576
#define BWIN (BB*NWIN)        // 1152
#define MLPH 768
#define EPS_ 1e-5f
#define NSIDE_TOK (BB*NTOK)   // 73728 tokens per side

typedef __attribute__((ext_vector_type(8))) short bf16x8;
typedef __attribute__((ext_vector_type(4))) float f32x4;

__device__ __forceinline__ unsigned short f2bf(float f) {
    __hip_bfloat16 h = __float2bfloat16(f);
    return *reinterpret_cast<unsigned short*>(&h);
}
__device__ __forceinline__ float gelu_exact(float x) {
    return 0.5f * x * (1.0f + erff(x * 0.70710678118654752f));
}

// ---------------- K1: LayerNorm1 -> bf16 ----------------
__global__ __launch_bounds__(256) void ln1_kernel(
    const float* __restrict__ xl, const float* __restrict__ xr,
    const float* __restrict__ g, const float* __restrict__ bta,
    __hip_bfloat16* __restrict__ xln_all)
{
    int token = blockIdx.x*4 + (threadIdx.x >> 6);
    int lane = threadIdx.x & 63;
    const float* src;
    __hip_bfloat16* dst;
    if (token < NSIDE_TOK) { src = xl + (size_t)token*CC; dst = xln_all + (size_t)token*CC; }
    else { int t2 = token - NSIDE_TOK; src = xr + (size_t)t2*CC; dst = xln_all + (size_t)token*CC; }
    float v0 = src[lane], v1 = src[lane+64], v2 = src[lane+128];
    float s = v0+v1+v2;
    #pragma unroll
    for (int m = 32; m; m >>= 1) s += __shfl_xor(s, m, 64);
    float mu = s * (1.0f/CC);
    float d0 = v0-mu, d1 = v1-mu, d2 = v2-mu;
    float q = d0*d0 + d1*d1 + d2*d2;
    #pragma unroll
    for (int m = 32; m; m >>= 1) q += __shfl_xor(q, m, 64);
    float inv = rsqrtf(q*(1.0f/CC) + EPS_);
    dst[lane]     = __float2bfloat16(d0*inv*g[lane]     + bta[lane]);
    dst[lane+64]  = __float2bfloat16(d1*inv*g[lane+64]  + bta[lane+64]);
    dst[lane+128] = __float2bfloat16(d2*inv*g[lane+128] + bta[lane+128]);
}

// ---------------- K2: epipolar gather (after LN) ----------------
// side 0: xsel_L = xr_ln gathered with r2l(d_left)   (KV source for left queries)
// side 1: xsel_R = xl_ln gathered with l2r(d_right)
__global__ __launch_bounds__(256) void gather_sel_kernel(
    const __hip_bfloat16* __restrict__ xln_all,
    const float* __restrict__ d_left, const float* __restrict__ d_right,
    __hip_bfloat16* __restrict__ xsel_all)
{
    int gid = blockIdx.x*256 + threadIdx.x;      // 2 * 73728 * 24
    int side = (gid >= NSIDE_TOK*24) ? 1 : 0;
    int rem = gid - side*NSIDE_TOK*24;
    int row = rem / 24, ch = rem - row*24;
    int j = row % WIMG;
    float d = side ? d_right[row] : d_left[row];
    int jj;
    if (!side) { float f = (float)j + 0.5f - d; f = fmaxf(f, 0.f); jj = (int)f; }
    else       { float f = (float)j + 0.5f + d; f = fminf(f, 191.f); jj = (int)f; }
    const __hip_bfloat16* srcb = xln_all + (side ? 0 : (size_t)NSIDE_TOK*CC);
    bf16x8 v = *reinterpret_cast<const bf16x8*>(srcb + (size_t)(row - j + jj)*CC + ch*8);
    *reinterpret_cast<bf16x8*>(xsel_all + (size_t)side*NSIDE_TOK*CC + (size_t)row*CC + ch*8) = v;
}

// ---------------- K3: convert/transpose all weights to bf16 [out][in] -------
__global__ __launch_bounds__(256) void conv_w_kernel(
    const float* __restrict__ q_w, const float* __restrict__ kv_w,
    const float* __restrict__ proj_w, const float* __restrict__ fc1_w,
    const float* __restrict__ fc2_w,
    __hip_bfloat16* __restrict__ q_wt, __hip_bfloat16* __restrict__ kv_wt,
    __hip_bfloat16* __restrict__ proj_wt, __hip_bfloat16* __restrict__ W1t,
    __hip_bfloat16* __restrict__ W2t)
{
    int idx = blockIdx.x*256 + threadIdx.x;   // total 442368
    if (idx < 36864) {
        int oc = idx/192, k = idx - oc*192;
        q_wt[idx] = __float2bfloat16(q_w[(size_t)k*192 + oc]);
    } else if (idx < 110592) {
        int j = idx - 36864; int oc = j/192, k = j - oc*192;
        kv_wt[j] = __float2bfloat16(kv_w[(size_t)k*384 + oc]);
    } else if (idx < 147456) {
        int j = idx - 110592; int oc = j/192, k = j - oc*192;
        proj_wt[j] = __float2bfloat16(proj_w[(size_t)k*192 + oc]);
    } else if (idx < 294912) {
        int j = idx - 147456; int oc = j/192, k = j - oc*192;
        W1t[j] = __float2bfloat16(fc1_w[(size_t)k*MLPH + oc]);
    } else {
        int j = idx - 294912; int oc = j/768, k = j - oc*768;
        W2t[j] = __float2bfloat16(fc2_w[(size_t)k*192 + oc]);
    }
}

// ---------------- K4: per-head rel-pos bias matrix [6][64][64] f32 ----------
__global__ __launch_bounds__(256) void bias_setup_kernel(
    const float* __restrict__ table, float* __restrict__ bias_glob)
{
    int idx = blockIdx.x*256 + threadIdx.x;   // 24576
    int h = idx >> 12, rem = idx & 4095;
    int q = rem >> 6, k = rem & 63;
    int qy = q>>3, qx = q&7, ky = k>>3, kx = k&7;
    int ridx = (qy-ky+7)*15 + (qx-kx+7);
    bias_glob[idx] = table[ridx*NHEADS + h];
}

// ---------------- K5: generic bf16 MFMA projection GEMM ----------------
// out[M][NT*16] = (in[M][192] @ W + bias) * scale, W given as Wt[N][192]
template<int NT>
__global__ __launch_bounds__(256) void proj_gemm_kernel(
    const __hip_bfloat16* __restrict__ in, const __hip_bfloat16* __restrict__ Wt,
    const float* __restrict__ bias, __hip_bfloat16* __restrict__ outp, float scale)
{
    __shared__ unsigned short xt[64*200];
    const int tid = threadIdx.x;
    const int lane = tid & 63, w = tid >> 6;
    const size_t baserow = (size_t)blockIdx.x * 64;
    #pragma unroll
    for (int it = 0; it < 6; ++it) {
        int idx = tid + it*256;
        int row = idx / 24, ch = idx - row*24;
        *reinterpret_cast<bf16x8*>(xt + row*200 + ch*8) =
            *reinterpret_cast<const bf16x8*>(in + (baserow+row)*CC + ch*8);
    }
    __syncthreads();
    const int r16 = lane & 15, kg = lane >> 4, w16 = w*16;
    f32x4 acc[NT];
    #pragma unroll
    for (int ct = 0; ct < NT; ++ct) {
        float bb = bias[ct*16 + r16];
        acc[ct] = (f32x4){bb,bb,bb,bb};
    }
    #pragma unroll
    for (int ks = 0; ks < 6; ++ks) {
        bf16x8 a = *reinterpret_cast<const bf16x8*>(xt + (w16+r16)*200 + ks*32 + kg*8);
        #pragma unroll
        for (int ct = 0; ct < NT; ++ct) {
            bf16x8 bb = *reinterpret_cast<const bf16x8*>(Wt + (size_t)(ct*16+r16)*192 + ks*32 + kg*8);
            acc[ct] = __builtin_amdgcn_mfma_f32_16x16x32_bf16(a, bb, acc[ct], 0, 0, 0);
        }
    }
    const int ldo = NT*16;
    #pragma unroll
    for (int ct = 0; ct < NT; ++ct)
        #pragma unroll
        for (int r = 0; r < 4; ++r)
            outp[(baserow + w16 + kg*4 + r)*ldo + ct*16 + r16] =
                __float2bfloat16(acc[ct][r] * scale);
}

// ---------------- K6: monolithic window attention (both sides + m + proj + fuse)
__global__ __launch_bounds__(256) void attn3_kernel(
    const __hip_bfloat16* __restrict__ Qglob,   // [2][73728][192]
    const __hip_bfloat16* __restrict__ KVglob,  // [2][73728][384]
    const __hip_bfloat16* __restrict__ xln_all, // [2][73728][192]
    const float* __restrict__ bias_glob,        // [6][64][64]
    const __hip_bfloat16* __restrict__ proj_wt, // [192][192]
    const float* __restrict__ proj_b,
    const float* __restrict__ x_left, const float* __restrict__ x_right,
    float* __restrict__ out)
{
    __shared__ int tok[64];
    __shared__ unsigned short Vt[32*72];        // [hd][key] per head-side
    __shared__ unsigned short Pb[2][64*72];     // probs bf16 [side][q][k]
    __shared__ unsigned short Tb[4][16*40];     // per-wave transpose scratch
    __shared__ float Gband[2][64][8];           // diag band of G
    __shared__ float mstore[2][6][64];          // m values [side][head][q]

    const int tid = threadIdx.x;
    const int lane = tid & 63, w = tid >> 6;
    const int r16 = lane & 15, kg = lane >> 4, w16 = w*16;
    const int widx = blockIdx.x;
    const int b = widx / NWIN, win = widx % NWIN;
    const int wi = win / NWX, wj = win % NWX;
    const bool edge_i = (wi == NWX-1), edge_j = (wj == NWX-1);

    if (tid < 64) {
        int p = tid;
        int rh = wi*8 + (p>>3), rw = wj*8 + (p&7);
        int i = rh + 4; if (i >= HH) i -= HH;
        int j = rw + 4; if (j >= WIMG) j -= WIMG;
        tok[p] = b*NTOK + i*WIMG + j;
    }
    __syncthreads();

    // cache the token indices each lane needs (constant across heads)
    const int tokA = tok[w16 + r16];            // A-frag rows (q strip)
    int tokB[4];
    #pragma unroll
    for (int ct = 0; ct < 4; ++ct) tokB[ct] = tok[ct*16 + r16];
    const int tokV = tok[tid >> 2];             // Vt staging
    int tokC[4];
    #pragma unroll
    for (int r = 0; r < 4; ++r) tokC[r] = tok[w16 + 4*kg + r];

    f32x4 pacc[2][12];
    #pragma unroll
    for (int s = 0; s < 2; ++s)
        #pragma unroll
        for (int ct = 0; ct < 12; ++ct) pacc[s][ct] = (f32x4){0.f,0.f,0.f,0.f};

    for (int h = 0; h < 6; ++h) {
        __syncthreads();  // A0: prev PV (Vt) + prev reduce (Gband) complete
        {   // zero Gband
            float* gz = &Gband[0][0][0];
            #pragma unroll
            for (int z = 0; z < 4; ++z) gz[tid + z*256] = 0.f;
        }

        #pragma unroll
        for (int s = 0; s < 2; ++s) {
            const __hip_bfloat16* Qg  = Qglob  + (size_t)s*NSIDE_TOK*CC;
            const __hip_bfloat16* KVg = KVglob + (size_t)s*NSIDE_TOK*(2*CC);

            // stage Vt[hd][key]
            {
                int dgr = (tid & 3)*8;
                bf16x8 vv = *reinterpret_cast<const bf16x8*>(
                    KVg + (size_t)tokV*(2*CC) + CC + h*HD + dgr);
                #pragma unroll
                for (int jj = 0; jj < 8; ++jj)
                    Vt[(dgr+jj)*72 + (tid>>2)] = (unsigned short)vv[jj];
            }

            // S strip = Q K^T  (16 q-rows x 64 keys per wave)
            bf16x8 aQ = *reinterpret_cast<const bf16x8*>(
                Qg + (size_t)tokA*CC + h*HD + kg*8);
            f32x4 sv[4];
            #pragma unroll
            for (int ct = 0; ct < 4; ++ct) {
                bf16x8 bK = *reinterpret_cast<const bf16x8*>(
                    KVg + (size_t)tokB[ct]*(2*CC) + h*HD + kg*8);
                sv[ct] = __builtin_amdgcn_mfma_f32_16x16x32_bf16(
                    aQ, bK, (f32x4){0.f,0.f,0.f,0.f}, 0, 0, 0);
            }
            // bias + mask
            #pragma unroll
            for (int ct = 0; ct < 4; ++ct) {
                #pragma unroll
                for (int r = 0; r < 4; ++r) {
                    int q = w16 + 4*kg + r, k = ct*16 + r16;
                    float bm = bias_glob[h*4096 + q*64 + k];
                    int qy = q>>3, qx = q&7, ky = k>>3, kx = k&7;
                    bool msk = (edge_i && ((qy<4) != (ky<4))) ||
                               (edge_j && ((qx<4) != (kx<4)));
                    sv[ct][r] += bm + (msk ? -100.0f : 0.0f);
                }
            }
            // softmax across k (r16 lanes x 4 ct), rows r
            float mx[4], sm[4];
            #pragma unroll
            for (int r = 0; r < 4; ++r) {
                mx[r] = fmaxf(fmaxf(sv[0][r], sv[1][r]), fmaxf(sv[2][r], sv[3][r]));
            }
            #pragma unroll
            for (int m = 1; m <= 8; m <<= 1)
                #pragma unroll
                for (int r = 0; r < 4; ++r) mx[r] = fmaxf(mx[r], __shfl_xor(mx[r], m, 64));
            #pragma unroll
            for (int r = 0; r < 4; ++r) sm[r] = 0.f;
            #pragma unroll
            for (int ct = 0; ct < 4; ++ct)
                #pragma unroll
                for (int r = 0; r < 4; ++r) {
                    sv[ct][r] = __expf(sv[ct][r] - mx[r]);
                    sm[r] += sv[ct][r];
                }
            #pragma unroll
            for (int m = 1; m <= 8; m <<= 1)
                #pragma unroll
                for (int r = 0; r < 4; ++r) sm[r] += __shfl_xor(sm[r], m, 64);
            #pragma unroll
            for (int r = 0; r < 4; ++r) sm[r] = 1.0f / sm[r];
            // P -> Pb[s]
            #pragma unroll
            for (int ct = 0; ct < 4; ++ct)
                #pragma unroll
                for (int r = 0; r < 4; ++r)
                    Pb[s][(w16 + 4*kg + r)*72 + ct*16 + r16] = f2bf(sv[ct][r]*sm[r]);

            __syncthreads();  // B: Vt ready, Pb strip written

            // PV: O strip 16 x 32
            f32x4 ov[2];
            #pragma unroll
            for (int ht = 0; ht < 2; ++ht) ov[ht] = (f32x4){0.f,0.f,0.f,0.f};
            #pragma unroll
            for (int ks = 0; ks < 2; ++ks) {
                bf16x8 aP = *reinterpret_cast<const bf16x8*>(
                    Pb[s] + (w16+r16)*72 + ks*32 + kg*8);
                #pragma unroll
                for (int ht = 0; ht < 2; ++ht) {
                    bf16x8 bV = *reinterpret_cast<const bf16x8*>(
                        Vt + (ht*16 + r16)*72 + ks*32 + kg*8);
                    ov[ht] = __builtin_amdgcn_mfma_f32_16x16x32_bf16(aP, bV, ov[ht], 0, 0, 0);
                }
            }
            // transpose O C-frag -> A-frag via wave-private Tb
            unsigned short* tb = &Tb[w][0];
            #pragma unroll
            for (int ht = 0; ht < 2; ++ht)
                #pragma unroll
                for (int r = 0; r < 4; ++r)
                    tb[(4*kg + r)*40 + ht*16 + r16] = f2bf(ov[ht][r]);
            __syncthreads();  // T: transpose visible (also guards Vt reuse)
            bf16x8 aO = *reinterpret_cast<const bf16x8*>(tb + r16*40 + kg*8);
            // proj partial: K-chunk h*32..+31
            #pragma unroll
            for (int ct = 0; ct < 12; ++ct) {
                bf16x8 bP = *reinterpret_cast<const bf16x8*>(
                    proj_wt + (size_t)(ct*16 + r16)*192 + h*HD + kg*8);
                pacc[s][ct] = __builtin_amdgcn_mfma_f32_16x16x32_bf16(aO, bP, pacc[s][ct], 0, 0, 0);
            }
        } // sides

        __syncthreads();  // D: Pb[0], Pb[1] complete
        // G_l = Pb0 @ Pb1 ; G_r = Pb1 @ Pb0 ; band extract
        #pragma unroll
        for (int gi = 0; gi < 2; ++gi) {
            const unsigned short* PbA = Pb[gi];
            const unsigned short* PbB = Pb[1-gi];
            f32x4 gv[4];
            #pragma unroll
            for (int ct = 0; ct < 4; ++ct) gv[ct] = (f32x4){0.f,0.f,0.f,0.f};
            #pragma unroll
            for (int ks = 0; ks < 2; ++ks) {
                bf16x8 aG = *reinterpret_cast<const bf16x8*>(
                    PbA + (w16+r16)*72 + ks*32 + kg*8);
                #pragma unroll
                for (int ct = 0; ct < 4; ++ct) {
                    bf16x8 bG;
                    const unsigned short* pcol = PbB + (ks*32 + kg*8)*72 + ct*16 + r16;
                    #pragma unroll
                    for (int jj = 0; jj < 8; ++jj) bG[jj] = (short)pcol[jj*72];
                    gv[ct] = __builtin_amdgcn_mfma_f32_16x16x32_bf16(aG, bG, gv[ct], 0, 0, 0);
                }
            }
            #pragma unroll
            for (int ct = 0; ct < 4; ++ct)
                #pragma unroll
                for (int r = 0; r < 4; ++r) {
                    int row = w16 + 4*kg + r, col = ct*16 + r16;
                    int d = row - col + 2;
                    if (d >= 0 && d < 5) Gband[gi][col][d] = gv[ct][r];
                }
        }
        __syncthreads();  // E
        if (tid < 128) {
            int s = tid >> 6, i = tid & 63;
            float s5 = Gband[s][i][0] + Gband[s][i][1] + Gband[s][i][2] +
                       Gband[s][i][3] + Gband[s][i][4];
            mstore[s][h][i] = tanhf(5.0f * s5);
        }
    } // heads

    __syncthreads();

    // epilogue: proj bias + fuse + window-reverse + residual
    #pragma unroll
    for (int s = 0; s < 2; ++s) {
        const __hip_bfloat16* xw_s = xln_all + (size_t)s*NSIDE_TOK*CC;
        const float* xo_s = s ? x_right : x_left;
        float* out_s = out + (size_t)s*NSIDE_TOK*CC;
        #pragma unroll
        for (int ct = 0; ct < 12; ++ct) {
            int col = ct*16 + r16;
            int hh = ct >> 1;
            float pb_ = proj_b[col];
            #pragma unroll
            for (int r = 0; r < 4; ++r) {
                int q = w16 + 4*kg + r;
                size_t t = (size_t)tokC[r];
                float p = pacc[s][ct][r] + pb_;
                float m = mstore[s][hh][q];
                float xw = __bfloat162float(xw_s[t*CC + col]);
                float xo = xo_s[t*CC + col];
                out_s[t*CC + col] = xo + xw + (p - xw)*m;
            }
        }
    }
}

// ---------------- K7: fused MLP via bf16 MFMA (round-2 proven) ----------------
__global__ __launch_bounds__(256) void mlp_mfma_kernel(
    float* __restrict__ out,
    const float* __restrict__ g2, const float* __restrict__ b2,
    const __hip_bfloat16* __restrict__ W1t, const float* __restrict__ fc1_b,
    const __hip_bfloat16* __restrict__ W2t, const float* __restrict__ fc2_b)
{
    __shared__ __hip_bfloat16 xt[64*200];
    __shared__ __hip_bfloat16 hbuf[64*72];
    const int tid  = threadIdx.x;
    const int lane = tid & 63;
    const int w    = tid >> 6;
    const size_t base = (size_t)blockIdx.x * 64 * CC;

    for (int t = 0; t < 16; ++t) {
        int row = w*16 + t;
        const float* src = out + base + (size_t)row*CC;
        float v0 = src[lane], v1 = src[lane+64], v2 = src[lane+128];
        float s = v0+v1+v2;
        #pragma unroll
        for (int m = 32; m; m >>= 1) s += __shfl_xor(s, m, 64);
        float mu = s * (1.0f/CC);
        float d0 = v0-mu, d1 = v1-mu, d2 = v2-mu;
        float q = d0*d0 + d1*d1 + d2*d2;
        #pragma unroll
        for (int m = 32; m; m >>= 1) q += __shfl_xor(q, m, 64);
        float inv = rsqrtf(q*(1.0f/CC) + EPS_);
        xt[row*200 + lane]       = __float2bfloat16(d0*inv*g2[lane]      + b2[lane]);
        xt[row*200 + lane + 64]  = __float2bfloat16(d1*inv*g2[lane+64]   + b2[lane+64]);
        xt[row*200 + lane + 128] = __float2bfloat16(d2*inv*g2[lane+128]  + b2[lane+128]);
    }

    const int r16 = lane & 15;
    const int kg  = lane >> 4;
    const int w16 = w * 16;

    f32x4 acc2[12];
    #pragma unroll
    for (int i = 0; i < 12; ++i) acc2[i] = (f32x4){0.f,0.f,0.f,0.f};

    for (int cc = 0; cc < 12; ++cc) {
        f32x4 acc1[4];
        #pragma unroll
        for (int ct = 0; ct < 4; ++ct) {
            float bb = fc1_b[cc*64 + ct*16 + r16];
            acc1[ct] = (f32x4){bb,bb,bb,bb};
        }
        #pragma unroll
        for (int ks = 0; ks < 6; ++ks) {
            bf16x8 a = *reinterpret_cast<const bf16x8*>(&xt[(w16 + r16)*200 + ks*32 + kg*8]);
            #pragma unroll
            for (int ct = 0; ct < 4; ++ct) {
                bf16x8 bw = *reinterpret_cast<const bf16x8*>(
                    &W1t[(size_t)(cc*64 + ct*16 + r16)*CC + ks*32 + kg*8]);
                acc1[ct] = __builtin_amdgcn_mfma_f32_16x16x32_bf16(a, bw, acc1[ct], 0, 0, 0);
            }
        }
        #pragma unroll
        for (int ct = 0; ct < 4; ++ct)
            #pragma unroll
            for (int r = 0; r < 4; ++r)
                hbuf[(w16 + kg*4 + r)*72 + ct*16 + r16] =
                    __float2bfloat16(gelu_exact(acc1[ct][r]));
        #pragma unroll
        for (int ks = 0; ks < 2; ++ks) {
            bf16x8 a2 = *reinterpret_cast<const bf16x8*>(&hbuf[(w16 + r16)*72 + ks*32 + kg*8]);
            #pragma unroll
            for (int ct = 0; ct < 12; ++ct) {
                bf16x8 bw = *reinterpret_cast<const bf16x8*>(
                    &W2t[(size_t)(ct*16 + r16)*MLPH + cc*64 + ks*32 + kg*8]);
                acc2[ct] = __builtin_amdgcn_mfma_f32_16x16x32_bf16(a2, bw, acc2[ct], 0, 0, 0);
            }
        }
    }

    #pragma unroll
    for (int ct = 0; ct < 12; ++ct) {
        int col = ct*16 + r16;
        float bb = fc2_b[col];
        #pragma unroll
        for (int r = 0; r < 4; ++r) {
            size_t idx = base + (size_t)(w16 + kg*4 + r)*CC + col;
            out[idx] = out[idx] + acc2[ct][r] + bb;
        }
    }
}

// ---------------- launch ----------------
extern "C" void kernel_launch(void* const* d_in, const int* in_sizes, int n_in,
                              void* d_out, int out_size, void* d_ws, size_t ws_size,
                              hipStream_t stream)
{
    (void)in_sizes; (void)n_in; (void)out_size; (void)ws_size;
    const float* x_left  = (const float*)d_in[0];
    const float* x_right = (const float*)d_in[1];
    const float* d_left  = (const float*)d_in[2];
    const float* d_right = (const float*)d_in[3];
    const float* n1g = (const float*)d_in[4];
    const float* n1b = (const float*)d_in[5];
    const float* q_w = (const float*)d_in[6];
    const float* q_b = (const float*)d_in[7];
    const float* kv_w = (const float*)d_in[8];
    const float* kv_b = (const float*)d_in[9];
    const float* proj_w = (const float*)d_in[10];
    const float* proj_b = (const float*)d_in[11];
    const float* bias_table = (const float*)d_in[12];
    const float* n2g = (const float*)d_in[13];
    const float* n2b = (const float*)d_in[14];
    const float* fc1_w = (const float*)d_in[15];
    const float* fc1_b = (const float*)d_in[16];
    const float* fc2_w = (const float*)d_in[17];
    const float* fc2_b = (const float*)d_in[18];
    float* out = (float*)d_out;

    char* ws = (char*)d_ws;
    __hip_bfloat16* xln_all  = (__hip_bfloat16*)(ws);                 // 56623104 B
    __hip_bfloat16* xsel_all = (__hip_bfloat16*)(ws + 56623104);      // 56623104 B
    __hip_bfloat16* Qg       = (__hip_bfloat16*)(ws + 56623104);      // aliases xsel (after KV gemm)
    __hip_bfloat16* KVg      = (__hip_bfloat16*)(ws + 113246208);     // 113246208 B
    __hip_bfloat16* q_wt     = (__hip_bfloat16*)(ws + 226492416);     // 73728 B
    __hip_bfloat16* kv_wt    = (__hip_bfloat16*)(ws + 226566144);     // 147456 B
    __hip_bfloat16* proj_wt  = (__hip_bfloat16*)(ws + 226713600);     // 73728 B
    __hip_bfloat16* W1t      = (__hip_bfloat16*)(ws + 226787328);     // 294912 B
    __hip_bfloat16* W2t      = (__hip_bfloat16*)(ws + 227082240);     // 294912 B
    float*          bias_g   = (float*)         (ws + 227377152);     // 393216 B

    ln1_kernel<<<(2*NSIDE_TOK)/4, 256, 0, stream>>>(x_left, x_right, n1g, n1b, xln_all);

    conv_w_kernel<<<1728, 256, 0, stream>>>(q_w, kv_w, proj_w, fc1_w, fc2_w,
                                            q_wt, kv_wt, proj_wt, W1t, W2t);
    bias_setup_kernel<<<96, 256, 0, stream>>>(bias_table, bias_g);

    gather_sel_kernel<<<(2*NSIDE_TOK*24)/256, 256, 0, stream>>>(
        xln_all, d_left, d_right, xsel_all);

    // KV = xsel @ kv_w + kv_b   (must run BEFORE Q gemm overwrites xsel region)
    proj_gemm_kernel<24><<<(2*NSIDE_TOK)/64, 256, 0, stream>>>(
        xsel_all, kv_wt, kv_b, KVg, 1.0f);
    // Q = (xln @ q_w + q_b) * scale
    proj_gemm_kernel<12><<<(2*NSIDE_TOK)/64, 256, 0, stream>>>(
        xln_all, q_wt, q_b, Qg, 0.17677669529663687f);

    attn3_kernel<<<BWIN, 256, 0, stream>>>(
        Qg, KVg, xln_all, bias_g, proj_wt, proj_b, x_left, x_right, out);

    mlp_mfma_kernel<<<(2*NSIDE_TOK)/64, 256, 0, stream>>>(
        out, n2g, n2b, W1t, fc1_b, W2t, fc2_b);
}

// Round 4
// 1069.383 us; speedup vs baseline: 15.0593x; 1.3779x over previous
//
#include <hip/hip_runtime.h>
#include <hip/hip_bf16.h>

#define BB 2
#define HH 192
#define WIMG 192
#define CC 192
#define NHEADS 6
#define HD 32
#define NTOK (HH*WIMG)        // 36864 tokens per image
#define NWX 24                // windows per axis
#define NWIN 576
#define BWIN (BB*NWIN)        // 1152
#define MLPH 768
#define EPS_ 1e-5f
#define NSIDE_TOK (BB*NTOK)   // 73728 tokens per side

typedef __attribute__((ext_vector_type(8))) short bf16x8;
typedef __attribute__((ext_vector_type(4))) float f32x4;

__device__ __forceinline__ unsigned short f2bf(float f) {
    __hip_bfloat16 h = __float2bfloat16(f);
    return *reinterpret_cast<unsigned short*>(&h);
}
// tanh-form GELU (max |err| vs exact ~3e-3; threshold 0.18)
__device__ __forceinline__ float gelu_fast(float x) {
    float z = 1.5957691216f*(x + 0.044715f*x*x*x);   // 2*sqrt(2/pi)*(...)
    float e = __expf(z);
    float t = 1.0f - 2.0f/(e + 1.0f);                // tanh(z/2*2)=tanh
    return 0.5f*x*(1.0f + t);
}

// ---------------- K1: LayerNorm1 -> bf16 ----------------
__global__ __launch_bounds__(256) void ln1_kernel(
    const float* __restrict__ xl, const float* __restrict__ xr,
    const float* __restrict__ g, const float* __restrict__ bta,
    __hip_bfloat16* __restrict__ xln_all)
{
    int token = blockIdx.x*4 + (threadIdx.x >> 6);
    int lane = threadIdx.x & 63;
    const float* src;
    __hip_bfloat16* dst;
    if (token < NSIDE_TOK) { src = xl + (size_t)token*CC; dst = xln_all + (size_t)token*CC; }
    else { int t2 = token - NSIDE_TOK; src = xr + (size_t)t2*CC; dst = xln_all + (size_t)token*CC; }
    float v0 = src[lane], v1 = src[lane+64], v2 = src[lane+128];
    float s = v0+v1+v2;
    #pragma unroll
    for (int m = 32; m; m >>= 1) s += __shfl_xor(s, m, 64);
    float mu = s * (1.0f/CC);
    float d0 = v0-mu, d1 = v1-mu, d2 = v2-mu;
    float q = d0*d0 + d1*d1 + d2*d2;
    #pragma unroll
    for (int m = 32; m; m >>= 1) q += __shfl_xor(q, m, 64);
    float inv = rsqrtf(q*(1.0f/CC) + EPS_);
    dst[lane]     = __float2bfloat16(d0*inv*g[lane]     + bta[lane]);
    dst[lane+64]  = __float2bfloat16(d1*inv*g[lane+64]  + bta[lane+64]);
    dst[lane+128] = __float2bfloat16(d2*inv*g[lane+128] + bta[lane+128]);
}

// ---------------- K2: epipolar gather (after LN) ----------------
__global__ __launch_bounds__(256) void gather_sel_kernel(
    const __hip_bfloat16* __restrict__ xln_all,
    const float* __restrict__ d_left, const float* __restrict__ d_right,
    __hip_bfloat16* __restrict__ xsel_all)
{
    int gid = blockIdx.x*256 + threadIdx.x;      // 2 * 73728 * 24
    int side = (gid >= NSIDE_TOK*24) ? 1 : 0;
    int rem = gid - side*NSIDE_TOK*24;
    int row = rem / 24, ch = rem - row*24;
    int j = row % WIMG;
    float d = side ? d_right[row] : d_left[row];
    int jj;
    if (!side) { float f = (float)j + 0.5f - d; f = fmaxf(f, 0.f); jj = (int)f; }
    else       { float f = (float)j + 0.5f + d; f = fminf(f, 191.f); jj = (int)f; }
    const __hip_bfloat16* srcb = xln_all + (side ? 0 : (size_t)NSIDE_TOK*CC);
    bf16x8 v = *reinterpret_cast<const bf16x8*>(srcb + (size_t)(row - j + jj)*CC + ch*8);
    *reinterpret_cast<bf16x8*>(xsel_all + (size_t)side*NSIDE_TOK*CC + (size_t)row*CC + ch*8) = v;
}

// ---------------- K3: convert weights to bf16 MFMA-FRAGMENT order ----------
// B-frag for mfma_16x16x32: lane holds 8 elems; n = ct*16 + (lane&15),
// k = ks*32 + (lane>>4)*8 + j.  Frag stored as Wf[frag*512 + lane*8 + j].
__global__ __launch_bounds__(256) void conv_w_kernel(
    const float* __restrict__ q_w, const float* __restrict__ kv_w,
    const float* __restrict__ proj_w, const float* __restrict__ fc1_w,
    const float* __restrict__ fc2_w,
    __hip_bfloat16* __restrict__ q_wf, __hip_bfloat16* __restrict__ kv_wf,
    __hip_bfloat16* __restrict__ proj_f, __hip_bfloat16* __restrict__ W1f,
    __hip_bfloat16* __restrict__ W2f)
{
    int idx = blockIdx.x*256 + threadIdx.x;   // total 442368
    if (idx < 36864) {
        // q_wf: frag = ks*12+ct  (NT=12)
        int j = idx & 7, lane = (idx>>3) & 63, fr = idx>>9;
        int ct = fr % 12, ks = fr / 12;
        int n = ct*16 + (lane&15), k = ks*32 + (lane>>4)*8 + j;
        q_wf[idx] = __float2bfloat16(q_w[(size_t)k*192 + n]);
    } else if (idx < 110592) {
        // kv_wf: frag = ks*24+ct  (NT=24)
        int i2 = idx - 36864;
        int j = i2 & 7, lane = (i2>>3) & 63, fr = i2>>9;
        int ct = fr % 24, ks = fr / 24;
        int n = ct*16 + (lane&15), k = ks*32 + (lane>>4)*8 + j;
        kv_wf[i2] = __float2bfloat16(kv_w[(size_t)k*384 + n]);
    } else if (idx < 147456) {
        // proj_f: frag = h*12+ct (K-chunk = head h, 32 wide)
        int i2 = idx - 110592;
        int j = i2 & 7, lane = (i2>>3) & 63, fr = i2>>9;
        int ct = fr % 12, h = fr / 12;
        int n = ct*16 + (lane&15), k = h*32 + (lane>>4)*8 + j;
        proj_f[i2] = __float2bfloat16(proj_w[(size_t)k*192 + n]);
    } else if (idx < 294912) {
        // W1f: frag = (cc*6+ks)*4+ct
        int i2 = idx - 147456;
        int j = i2 & 7, lane = (i2>>3) & 63, fr = i2>>9;
        int ct = fr % 4, ks = (fr/4) % 6, cc = fr / 24;
        int n = cc*64 + ct*16 + (lane&15), k = ks*32 + (lane>>4)*8 + j;
        W1f[i2] = __float2bfloat16(fc1_w[(size_t)k*MLPH + n]);
    } else {
        // W2f: frag = (cc*2+ks)*12+ct
        int i2 = idx - 294912;
        int j = i2 & 7, lane = (i2>>3) & 63, fr = i2>>9;
        int ct = fr % 12, ks = (fr/12) % 2, cc = fr / 24;
        int n = ct*16 + (lane&15), k = cc*64 + ks*32 + (lane>>4)*8 + j;
        W2f[i2] = __float2bfloat16(fc2_w[(size_t)k*192 + n]);
    }
}

// ---------------- K4: per-head rel-pos bias matrix [6][64][64] f32 ----------
__global__ __launch_bounds__(256) void bias_setup_kernel(
    const float* __restrict__ table, float* __restrict__ bias_glob)
{
    int idx = blockIdx.x*256 + threadIdx.x;   // 24576
    int h = idx >> 12, rem = idx & 4095;
    int q = rem >> 6, k = rem & 63;
    int qy = q>>3, qx = q&7, ky = k>>3, kx = k&7;
    int ridx = (qy-ky+7)*15 + (qx-kx+7);
    bias_glob[idx] = table[ridx*NHEADS + h];
}

// ---------------- K5: generic bf16 MFMA projection GEMM (frag weights) ------
template<int NT>
__global__ __launch_bounds__(256) void proj_gemm_kernel(
    const __hip_bfloat16* __restrict__ in, const __hip_bfloat16* __restrict__ Wf,
    const float* __restrict__ bias, __hip_bfloat16* __restrict__ outp, float scale)
{
    __shared__ unsigned short xt[64*200];
    const int tid = threadIdx.x;
    const int lane = tid & 63, w = tid >> 6;
    const size_t baserow = (size_t)blockIdx.x * 64;
    #pragma unroll
    for (int it = 0; it < 6; ++it) {
        int idx = tid + it*256;
        int row = idx / 24, ch = idx - row*24;
        *reinterpret_cast<bf16x8*>(xt + row*200 + ch*8) =
            *reinterpret_cast<const bf16x8*>(in + (baserow+row)*CC + ch*8);
    }
    __syncthreads();
    const int r16 = lane & 15, kg = lane >> 4, w16 = w*16;
    f32x4 acc[NT];
    #pragma unroll
    for (int ct = 0; ct < NT; ++ct) {
        float bb = bias[ct*16 + r16];
        acc[ct] = (f32x4){bb,bb,bb,bb};
    }
    #pragma unroll
    for (int ks = 0; ks < 6; ++ks) {
        bf16x8 a = *reinterpret_cast<const bf16x8*>(xt + (w16+r16)*200 + ks*32 + kg*8);
        #pragma unroll
        for (int ct = 0; ct < NT; ++ct) {
            bf16x8 bb = *reinterpret_cast<const bf16x8*>(Wf + ((ks*NT + ct)<<9) + lane*8);
            acc[ct] = __builtin_amdgcn_mfma_f32_16x16x32_bf16(a, bb, acc[ct], 0, 0, 0);
        }
    }
    const int ldo = NT*16;
    #pragma unroll
    for (int ct = 0; ct < NT; ++ct)
        #pragma unroll
        for (int r = 0; r < 4; ++r)
            outp[(baserow + w16 + kg*4 + r)*ldo + ct*16 + r16] =
                __float2bfloat16(acc[ct][r] * scale);
}

// ---------------- K6: monolithic window attention (both sides + m + proj + fuse)
__global__ __launch_bounds__(256) void attn3_kernel(
    const __hip_bfloat16* __restrict__ Qglob,   // [2][73728][192]
    const __hip_bfloat16* __restrict__ KVglob,  // [2][73728][384]
    const __hip_bfloat16* __restrict__ xln_all, // [2][73728][192]
    const float* __restrict__ bias_glob,        // [6][64][64]
    const __hip_bfloat16* __restrict__ proj_f,  // frag-ordered
    const float* __restrict__ proj_b,
    const float* __restrict__ x_left, const float* __restrict__ x_right,
    float* __restrict__ out)
{
    __shared__ int tok[64];
    __shared__ unsigned short Vt[32*72];
    __shared__ unsigned short Pb[2][64*72];
    __shared__ unsigned short Tb[4][16*40];
    __shared__ float Gband[2][64][8];
    __shared__ float mstore[2][6][64];

    const int tid = threadIdx.x;
    const int lane = tid & 63, w = tid >> 6;
    const int r16 = lane & 15, kg = lane >> 4, w16 = w*16;
    const int widx = blockIdx.x;
    const int b = widx / NWIN, win = widx % NWIN;
    const int wi = win / NWX, wj = win % NWX;
    const bool edge_i = (wi == NWX-1), edge_j = (wj == NWX-1);

    if (tid < 64) {
        int p = tid;
        int rh = wi*8 + (p>>3), rw = wj*8 + (p&7);
        int i = rh + 4; if (i >= HH) i -= HH;
        int j = rw + 4; if (j >= WIMG) j -= WIMG;
        tok[p] = b*NTOK + i*WIMG + j;
    }
    __syncthreads();

    const int tokA = tok[w16 + r16];
    int tokB[4];
    #pragma unroll
    for (int ct = 0; ct < 4; ++ct) tokB[ct] = tok[ct*16 + r16];
    const int tokV = tok[tid >> 2];
    int tokC[4];
    #pragma unroll
    for (int r = 0; r < 4; ++r) tokC[r] = tok[w16 + 4*kg + r];

    f32x4 pacc[2][12];
    #pragma unroll
    for (int s = 0; s < 2; ++s)
        #pragma unroll
        for (int ct = 0; ct < 12; ++ct) pacc[s][ct] = (f32x4){0.f,0.f,0.f,0.f};

    for (int h = 0; h < 6; ++h) {
        __syncthreads();
        {
            float* gz = &Gband[0][0][0];
            #pragma unroll
            for (int z = 0; z < 4; ++z) gz[tid + z*256] = 0.f;
        }

        #pragma unroll
        for (int s = 0; s < 2; ++s) {
            const __hip_bfloat16* Qg  = Qglob  + (size_t)s*NSIDE_TOK*CC;
            const __hip_bfloat16* KVg = KVglob + (size_t)s*NSIDE_TOK*(2*CC);

            {
                int dgr = (tid & 3)*8;
                bf16x8 vv = *reinterpret_cast<const bf16x8*>(
                    KVg + (size_t)tokV*(2*CC) + CC + h*HD + dgr);
                #pragma unroll
                for (int jj = 0; jj < 8; ++jj)
                    Vt[(dgr+jj)*72 + (tid>>2)] = (unsigned short)vv[jj];
            }

            bf16x8 aQ = *reinterpret_cast<const bf16x8*>(
                Qg + (size_t)tokA*CC + h*HD + kg*8);
            f32x4 sv[4];
            #pragma unroll
            for (int ct = 0; ct < 4; ++ct) {
                bf16x8 bK = *reinterpret_cast<const bf16x8*>(
                    KVg + (size_t)tokB[ct]*(2*CC) + h*HD + kg*8);
                sv[ct] = __builtin_amdgcn_mfma_f32_16x16x32_bf16(
                    aQ, bK, (f32x4){0.f,0.f,0.f,0.f}, 0, 0, 0);
            }
            #pragma unroll
            for (int ct = 0; ct < 4; ++ct) {
                #pragma unroll
                for (int r = 0; r < 4; ++r) {
                    int q = w16 + 4*kg + r, k = ct*16 + r16;
                    float bm = bias_glob[h*4096 + q*64 + k];
                    int qy = q>>3, qx = q&7, ky = k>>3, kx = k&7;
                    bool msk = (edge_i && ((qy<4) != (ky<4))) ||
                               (edge_j && ((qx<4) != (kx<4)));
                    sv[ct][r] += bm + (msk ? -100.0f : 0.0f);
                }
            }
            float mx[4], sm[4];
            #pragma unroll
            for (int r = 0; r < 4; ++r) {
                mx[r] = fmaxf(fmaxf(sv[0][r], sv[1][r]), fmaxf(sv[2][r], sv[3][r]));
            }
            #pragma unroll
            for (int m = 1; m <= 8; m <<= 1)
                #pragma unroll
                for (int r = 0; r < 4; ++r) mx[r] = fmaxf(mx[r], __shfl_xor(mx[r], m, 64));
            #pragma unroll
            for (int r = 0; r < 4; ++r) sm[r] = 0.f;
            #pragma unroll
            for (int ct = 0; ct < 4; ++ct)
                #pragma unroll
                for (int r = 0; r < 4; ++r) {
                    sv[ct][r] = __expf(sv[ct][r] - mx[r]);
                    sm[r] += sv[ct][r];
                }
            #pragma unroll
            for (int m = 1; m <= 8; m <<= 1)
                #pragma unroll
                for (int r = 0; r < 4; ++r) sm[r] += __shfl_xor(sm[r], m, 64);
            #pragma unroll
            for (int r = 0; r < 4; ++r) sm[r] = 1.0f / sm[r];
            #pragma unroll
            for (int ct = 0; ct < 4; ++ct)
                #pragma unroll
                for (int r = 0; r < 4; ++r)
                    Pb[s][(w16 + 4*kg + r)*72 + ct*16 + r16] = f2bf(sv[ct][r]*sm[r]);

            __syncthreads();

            f32x4 ov[2];
            #pragma unroll
            for (int ht = 0; ht < 2; ++ht) ov[ht] = (f32x4){0.f,0.f,0.f,0.f};
            #pragma unroll
            for (int ks = 0; ks < 2; ++ks) {
                bf16x8 aP = *reinterpret_cast<const bf16x8*>(
                    Pb[s] + (w16+r16)*72 + ks*32 + kg*8);
                #pragma unroll
                for (int ht = 0; ht < 2; ++ht) {
                    bf16x8 bV = *reinterpret_cast<const bf16x8*>(
                        Vt + (ht*16 + r16)*72 + ks*32 + kg*8);
                    ov[ht] = __builtin_amdgcn_mfma_f32_16x16x32_bf16(aP, bV, ov[ht], 0, 0, 0);
                }
            }
            unsigned short* tb = &Tb[w][0];
            #pragma unroll
            for (int ht = 0; ht < 2; ++ht)
                #pragma unroll
                for (int r = 0; r < 4; ++r)
                    tb[(4*kg + r)*40 + ht*16 + r16] = f2bf(ov[ht][r]);
            __syncthreads();
            bf16x8 aO = *reinterpret_cast<const bf16x8*>(tb + r16*40 + kg*8);
            #pragma unroll
            for (int ct = 0; ct < 12; ++ct) {
                bf16x8 bP = *reinterpret_cast<const bf16x8*>(
                    proj_f + ((h*12 + ct)<<9) + lane*8);
                pacc[s][ct] = __builtin_amdgcn_mfma_f32_16x16x32_bf16(aO, bP, pacc[s][ct], 0, 0, 0);
            }
        } // sides

        __syncthreads();
        #pragma unroll
        for (int gi = 0; gi < 2; ++gi) {
            const unsigned short* PbA = Pb[gi];
            const unsigned short* PbB = Pb[1-gi];
            f32x4 gv[4];
            #pragma unroll
            for (int ct = 0; ct < 4; ++ct) gv[ct] = (f32x4){0.f,0.f,0.f,0.f};
            #pragma unroll
            for (int ks = 0; ks < 2; ++ks) {
                bf16x8 aG = *reinterpret_cast<const bf16x8*>(
                    PbA + (w16+r16)*72 + ks*32 + kg*8);
                #pragma unroll
                for (int ct = 0; ct < 4; ++ct) {
                    bf16x8 bG;
                    const unsigned short* pcol = PbB + (ks*32 + kg*8)*72 + ct*16 + r16;
                    #pragma unroll
                    for (int jj = 0; jj < 8; ++jj) bG[jj] = (short)pcol[jj*72];
                    gv[ct] = __builtin_amdgcn_mfma_f32_16x16x32_bf16(aG, bG, gv[ct], 0, 0, 0);
                }
            }
            #pragma unroll
            for (int ct = 0; ct < 4; ++ct)
                #pragma unroll
                for (int r = 0; r < 4; ++r) {
                    int row = w16 + 4*kg + r, col = ct*16 + r16;
                    int d = row - col + 2;
                    if (d >= 0 && d < 5) Gband[gi][col][d] = gv[ct][r];
                }
        }
        __syncthreads();
        if (tid < 128) {
            int s = tid >> 6, i = tid & 63;
            float s5 = Gband[s][i][0] + Gband[s][i][1] + Gband[s][i][2] +
                       Gband[s][i][3] + Gband[s][i][4];
            mstore[s][h][i] = tanhf(5.0f * s5);
        }
    } // heads

    __syncthreads();

    #pragma unroll
    for (int s = 0; s < 2; ++s) {
        const __hip_bfloat16* xw_s = xln_all + (size_t)s*NSIDE_TOK*CC;
        const float* xo_s = s ? x_right : x_left;
        float* out_s = out + (size_t)s*NSIDE_TOK*CC;
        #pragma unroll
        for (int ct = 0; ct < 12; ++ct) {
            int col = ct*16 + r16;
            int hh = ct >> 1;
            float pb_ = proj_b[col];
            #pragma unroll
            for (int r = 0; r < 4; ++r) {
                int q = w16 + 4*kg + r;
                size_t t = (size_t)tokC[r];
                float p = pacc[s][ct][r] + pb_;
                float m = mstore[s][hh][q];
                float xw = __bfloat162float(xw_s[t*CC + col]);
                float xo = xo_s[t*CC + col];
                out_s[t*CC + col] = xo + xw + (p - xw)*m;
            }
        }
    }
}

// ---------------- K7: fused MLP via bf16 MFMA (frag-ordered weights) --------
__global__ __launch_bounds__(256) void mlp_mfma_kernel(
    float* __restrict__ out,
    const float* __restrict__ g2, const float* __restrict__ b2,
    const __hip_bfloat16* __restrict__ W1f, const float* __restrict__ fc1_b,
    const __hip_bfloat16* __restrict__ W2f, const float* __restrict__ fc2_b)
{
    __shared__ __hip_bfloat16 xt[64*200];
    __shared__ __hip_bfloat16 hbuf[64*72];
    const int tid  = threadIdx.x;
    const int lane = tid & 63;
    const int w    = tid >> 6;
    const size_t base = (size_t)blockIdx.x * 64 * CC;

    for (int t = 0; t < 16; ++t) {
        int row = w*16 + t;
        const float* src = out + base + (size_t)row*CC;
        float v0 = src[lane], v1 = src[lane+64], v2 = src[lane+128];
        float s = v0+v1+v2;
        #pragma unroll
        for (int m = 32; m; m >>= 1) s += __shfl_xor(s, m, 64);
        float mu = s * (1.0f/CC);
        float d0 = v0-mu, d1 = v1-mu, d2 = v2-mu;
        float q = d0*d0 + d1*d1 + d2*d2;
        #pragma unroll
        for (int m = 32; m; m >>= 1) q += __shfl_xor(q, m, 64);
        float inv = rsqrtf(q*(1.0f/CC) + EPS_);
        xt[row*200 + lane]       = __float2bfloat16(d0*inv*g2[lane]      + b2[lane]);
        xt[row*200 + lane + 64]  = __float2bfloat16(d1*inv*g2[lane+64]   + b2[lane+64]);
        xt[row*200 + lane + 128] = __float2bfloat16(d2*inv*g2[lane+128]  + b2[lane+128]);
    }

    const int r16 = lane & 15;
    const int kg  = lane >> 4;
    const int w16 = w * 16;

    f32x4 acc2[12];
    #pragma unroll
    for (int i = 0; i < 12; ++i) acc2[i] = (f32x4){0.f,0.f,0.f,0.f};

    for (int cc = 0; cc < 12; ++cc) {
        f32x4 acc1[4];
        #pragma unroll
        for (int ct = 0; ct < 4; ++ct) {
            float bb = fc1_b[cc*64 + ct*16 + r16];
            acc1[ct] = (f32x4){bb,bb,bb,bb};
        }
        #pragma unroll
        for (int ks = 0; ks < 6; ++ks) {
            bf16x8 a = *reinterpret_cast<const bf16x8*>(&xt[(w16 + r16)*200 + ks*32 + kg*8]);
            #pragma unroll
            for (int ct = 0; ct < 4; ++ct) {
                bf16x8 bw = *reinterpret_cast<const bf16x8*>(
                    W1f + ((((cc*6 + ks)*4 + ct))<<9) + lane*8);
                acc1[ct] = __builtin_amdgcn_mfma_f32_16x16x32_bf16(a, bw, acc1[ct], 0, 0, 0);
            }
        }
        #pragma unroll
        for (int ct = 0; ct < 4; ++ct)
            #pragma unroll
            for (int r = 0; r < 4; ++r)
                hbuf[(w16 + kg*4 + r)*72 + ct*16 + r16] =
                    __float2bfloat16(gelu_fast(acc1[ct][r]));
        #pragma unroll
        for (int ks = 0; ks < 2; ++ks) {
            bf16x8 a2 = *reinterpret_cast<const bf16x8*>(&hbuf[(w16 + r16)*72 + ks*32 + kg*8]);
            #pragma unroll
            for (int ct = 0; ct < 12; ++ct) {
                bf16x8 bw = *reinterpret_cast<const bf16x8*>(
                    W2f + ((((cc*2 + ks)*12 + ct))<<9) + lane*8);
                acc2[ct] = __builtin_amdgcn_mfma_f32_16x16x32_bf16(a2, bw, acc2[ct], 0, 0, 0);
            }
        }
    }

    #pragma unroll
    for (int ct = 0; ct < 12; ++ct) {
        int col = ct*16 + r16;
        float bb = fc2_b[col];
        #pragma unroll
        for (int r = 0; r < 4; ++r) {
            size_t idx = base + (size_t)(w16 + kg*4 + r)*CC + col;
            out[idx] = out[idx] + acc2[ct][r] + bb;
        }
    }
}

// ---------------- launch ----------------
extern "C" void kernel_launch(void* const* d_in, const int* in_sizes, int n_in,
                              void* d_out, int out_size, void* d_ws, size_t ws_size,
                              hipStream_t stream)
{
    (void)in_sizes; (void)n_in; (void)out_size; (void)ws_size;
    const float* x_left  = (const float*)d_in[0];
    const float* x_right = (const float*)d_in[1];
    const float* d_left  = (const float*)d_in[2];
    const float* d_right = (const float*)d_in[3];
    const float* n1g = (const float*)d_in[4];
    const float* n1b = (const float*)d_in[5];
    const float* q_w = (const float*)d_in[6];
    const float* q_b = (const float*)d_in[7];
    const float* kv_w = (const float*)d_in[8];
    const float* kv_b = (const float*)d_in[9];
    const float* proj_w = (const float*)d_in[10];
    const float* proj_b = (const float*)d_in[11];
    const float* bias_table = (const float*)d_in[12];
    const float* n2g = (const float*)d_in[13];
    const float* n2b = (const float*)d_in[14];
    const float* fc1_w = (const float*)d_in[15];
    const float* fc1_b = (const float*)d_in[16];
    const float* fc2_w = (const float*)d_in[17];
    const float* fc2_b = (const float*)d_in[18];
    float* out = (float*)d_out;

    char* ws = (char*)d_ws;
    __hip_bfloat16* xln_all  = (__hip_bfloat16*)(ws);                 // 56623104 B
    __hip_bfloat16* xsel_all = (__hip_bfloat16*)(ws + 56623104);      // 56623104 B
    __hip_bfloat16* Qg       = (__hip_bfloat16*)(ws + 56623104);      // aliases xsel (after KV gemm)
    __hip_bfloat16* KVg      = (__hip_bfloat16*)(ws + 113246208);     // 113246208 B
    __hip_bfloat16* q_wf     = (__hip_bfloat16*)(ws + 226492416);     // 73728 B
    __hip_bfloat16* kv_wf    = (__hip_bfloat16*)(ws + 226566144);     // 147456 B
    __hip_bfloat16* proj_f   = (__hip_bfloat16*)(ws + 226713600);     // 73728 B
    __hip_bfloat16* W1f      = (__hip_bfloat16*)(ws + 226787328);     // 294912 B
    __hip_bfloat16* W2f      = (__hip_bfloat16*)(ws + 227082240);     // 294912 B
    float*          bias_g   = (float*)         (ws + 227377152);     // 393216 B

    ln1_kernel<<<(2*NSIDE_TOK)/4, 256, 0, stream>>>(x_left, x_right, n1g, n1b, xln_all);

    conv_w_kernel<<<1728, 256, 0, stream>>>(q_w, kv_w, proj_w, fc1_w, fc2_w,
                                            q_wf, kv_wf, proj_f, W1f, W2f);
    bias_setup_kernel<<<96, 256, 0, stream>>>(bias_table, bias_g);

    gather_sel_kernel<<<(2*NSIDE_TOK*24)/256, 256, 0, stream>>>(
        xln_all, d_left, d_right, xsel_all);

    proj_gemm_kernel<24><<<(2*NSIDE_TOK)/64, 256, 0, stream>>>(
        xsel_all, kv_wf, kv_b, KVg, 1.0f);
    proj_gemm_kernel<12><<<(2*NSIDE_TOK)/64, 256, 0, stream>>>(
        xln_all, q_wf, q_b, Qg, 0.17677669529663687f);

    attn3_kernel<<<BWIN, 256, 0, stream>>>(
        Qg, KVg, xln_all, bias_g, proj_f, proj_b, x_left, x_right, out);

    mlp_mfma_kernel<<<(2*NSIDE_TOK)/64, 256, 0, stream>>>(
        out, n2g, n2b, W1f, fc1_b, W2f, fc2_b);
}

// Round 5
// 729.514 us; speedup vs baseline: 22.0752x; 1.4659x over previous
//
#include <hip/hip_runtime.h>
#include <hip/hip_bf16.h>

#define BB 2
#define HH 192
#define WIMG 192
#define CC 192
#define NHEADS 6
#define HD 32
#define NTOK (HH*WIMG)        // 36864 tokens per image
#define NWX 24                // windows per axis
#define NWIN 576
#define BWIN (BB*NWIN)        // 1152
#define MLPH 768
#define EPS_ 1e-5f
#define NSIDE_TOK (BB*NTOK)   // 73728 tokens per side

typedef __attribute__((ext_vector_type(8))) short bf16x8;
typedef __attribute__((ext_vector_type(4))) float f32x4;

#define GLOBAL_AS __attribute__((address_space(1)))
#define LDS_AS __attribute__((address_space(3)))
__device__ __forceinline__ void gll16(const void* g, void* l) {
    __builtin_amdgcn_global_load_lds((const GLOBAL_AS unsigned int*)g,
                                     (LDS_AS unsigned int*)l, 16, 0, 0);
}

__device__ __forceinline__ unsigned short f2bf(float f) {
    __hip_bfloat16 h = __float2bfloat16(f);
    return *reinterpret_cast<unsigned short*>(&h);
}
// tanh-form GELU (max |err| vs exact ~3e-3; threshold 0.18)
__device__ __forceinline__ float gelu_fast(float x) {
    float z = 1.5957691216f*(x + 0.044715f*x*x*x);
    float e = __expf(z);
    float t = 1.0f - 2.0f/(e + 1.0f);
    return 0.5f*x*(1.0f + t);
}

// ---------------- K1: LayerNorm1 -> bf16 ----------------
__global__ __launch_bounds__(256) void ln1_kernel(
    const float* __restrict__ xl, const float* __restrict__ xr,
    const float* __restrict__ g, const float* __restrict__ bta,
    __hip_bfloat16* __restrict__ xln_all)
{
    int token = blockIdx.x*4 + (threadIdx.x >> 6);
    int lane = threadIdx.x & 63;
    const float* src;
    __hip_bfloat16* dst;
    if (token < NSIDE_TOK) { src = xl + (size_t)token*CC; dst = xln_all + (size_t)token*CC; }
    else { int t2 = token - NSIDE_TOK; src = xr + (size_t)t2*CC; dst = xln_all + (size_t)token*CC; }
    float v0 = src[lane], v1 = src[lane+64], v2 = src[lane+128];
    float s = v0+v1+v2;
    float q = v0*v0 + v1*v1 + v2*v2;
    #pragma unroll
    for (int m = 32; m; m >>= 1) { s += __shfl_xor(s, m, 64); q += __shfl_xor(q, m, 64); }
    float mu = s * (1.0f/CC);
    float inv = rsqrtf(fmaxf(q*(1.0f/CC) - mu*mu, 0.0f) + EPS_);
    dst[lane]     = __float2bfloat16((v0-mu)*inv*g[lane]     + bta[lane]);
    dst[lane+64]  = __float2bfloat16((v1-mu)*inv*g[lane+64]  + bta[lane+64]);
    dst[lane+128] = __float2bfloat16((v2-mu)*inv*g[lane+128] + bta[lane+128]);
}

// ---------------- K2: epipolar gather (after LN) ----------------
__global__ __launch_bounds__(256) void gather_sel_kernel(
    const __hip_bfloat16* __restrict__ xln_all,
    const float* __restrict__ d_left, const float* __restrict__ d_right,
    __hip_bfloat16* __restrict__ xsel_all)
{
    int gid = blockIdx.x*256 + threadIdx.x;      // 2 * 73728 * 24
    int side = (gid >= NSIDE_TOK*24) ? 1 : 0;
    int rem = gid - side*NSIDE_TOK*24;
    int row = rem / 24, ch = rem - row*24;
    int j = row % WIMG;
    float d = side ? d_right[row] : d_left[row];
    int jj;
    if (!side) { float f = (float)j + 0.5f - d; f = fmaxf(f, 0.f); jj = (int)f; }
    else       { float f = (float)j + 0.5f + d; f = fminf(f, 191.f); jj = (int)f; }
    const __hip_bfloat16* srcb = xln_all + (side ? 0 : (size_t)NSIDE_TOK*CC);
    bf16x8 v = *reinterpret_cast<const bf16x8*>(srcb + (size_t)(row - j + jj)*CC + ch*8);
    *reinterpret_cast<bf16x8*>(xsel_all + (size_t)side*NSIDE_TOK*CC + (size_t)row*CC + ch*8) = v;
}

// ---------------- K3: convert weights to bf16 MFMA-FRAGMENT order ----------
// B-frag for mfma_16x16x32: lane holds 8 elems; frag stored Wf[frag*512+lane*8+j]
// W1f NEW order: chunk cc2 (32 hidden cols) of 12 frags: frag=(cc2*6+ks)*2+ct
__global__ __launch_bounds__(256) void conv_w_kernel(
    const float* __restrict__ q_w, const float* __restrict__ kv_w,
    const float* __restrict__ proj_w, const float* __restrict__ fc1_w,
    const float* __restrict__ fc2_w,
    __hip_bfloat16* __restrict__ q_wf, __hip_bfloat16* __restrict__ kv_wf,
    __hip_bfloat16* __restrict__ proj_f, __hip_bfloat16* __restrict__ W1f,
    __hip_bfloat16* __restrict__ W2f)
{
    int idx = blockIdx.x*256 + threadIdx.x;   // total 442368
    if (idx < 36864) {
        int j = idx & 7, lane = (idx>>3) & 63, fr = idx>>9;
        int ct = fr % 12, ks = fr / 12;
        int n = ct*16 + (lane&15), k = ks*32 + (lane>>4)*8 + j;
        q_wf[idx] = __float2bfloat16(q_w[(size_t)k*192 + n]);
    } else if (idx < 110592) {
        int i2 = idx - 36864;
        int j = i2 & 7, lane = (i2>>3) & 63, fr = i2>>9;
        int ct = fr % 24, ks = fr / 24;
        int n = ct*16 + (lane&15), k = ks*32 + (lane>>4)*8 + j;
        kv_wf[i2] = __float2bfloat16(kv_w[(size_t)k*384 + n]);
    } else if (idx < 147456) {
        int i2 = idx - 110592;
        int j = i2 & 7, lane = (i2>>3) & 63, fr = i2>>9;
        int ct = fr % 12, h = fr / 12;
        int n = ct*16 + (lane&15), k = h*32 + (lane>>4)*8 + j;
        proj_f[i2] = __float2bfloat16(proj_w[(size_t)k*192 + n]);
    } else if (idx < 294912) {
        // W1f: frag = (cc2*6 + ks)*2 + ct,  cc2 in [0,24), ct in [0,2)
        int i2 = idx - 147456;
        int j = i2 & 7, lane = (i2>>3) & 63, fr = i2>>9;
        int ct = fr & 1, ks = (fr>>1) % 6, cc2 = fr / 12;
        int n = cc2*32 + ct*16 + (lane&15), k = ks*32 + (lane>>4)*8 + j;
        W1f[i2] = __float2bfloat16(fc1_w[(size_t)k*MLPH + n]);
    } else {
        // W2f: frag = (cc*2+ks)*12+ct  (12KB chunk per (cc,ks))
        int i2 = idx - 294912;
        int j = i2 & 7, lane = (i2>>3) & 63, fr = i2>>9;
        int ct = fr % 12, ks = (fr/12) % 2, cc = fr / 24;
        int n = ct*16 + (lane&15), k = cc*64 + ks*32 + (lane>>4)*8 + j;
        W2f[i2] = __float2bfloat16(fc2_w[(size_t)k*192 + n]);
    }
}

// ---------------- K4: per-head rel-pos bias matrix [6][64][64] f32 ----------
__global__ __launch_bounds__(256) void bias_setup_kernel(
    const float* __restrict__ table, float* __restrict__ bias_glob)
{
    int idx = blockIdx.x*256 + threadIdx.x;   // 24576
    int h = idx >> 12, rem = idx & 4095;
    int q = rem >> 6, k = rem & 63;
    int qy = q>>3, qx = q&7, ky = k>>3, kx = k&7;
    int ridx = (qy-ky+7)*15 + (qx-kx+7);
    bias_glob[idx] = table[ridx*NHEADS + h];
}

// ---------------- K5: bf16 MFMA projection GEMM (A in regs, W staged in LDS)
template<int NT>
__global__ __launch_bounds__(256) void proj_gemm_kernel(
    const __hip_bfloat16* __restrict__ in, const __hip_bfloat16* __restrict__ Wf,
    const float* __restrict__ bias, __hip_bfloat16* __restrict__ outp, float scale)
{
    __shared__ unsigned short wst[2][NT*512];
    const int tid = threadIdx.x, lane = tid & 63, w = tid >> 6;
    const int r16 = lane & 15, kg = lane >> 4, w16 = w*16;
    const size_t baserow = (size_t)blockIdx.x * 64;
    const size_t row = baserow + w16 + r16;

    bf16x8 aReg[6];
    #pragma unroll
    for (int ks = 0; ks < 6; ++ks)
        aReg[ks] = *reinterpret_cast<const bf16x8*>(in + row*CC + ks*32 + kg*8);

    const char* wsrc = (const char*)Wf;
    const int soff = w*1024 + lane*16;
    #pragma unroll
    for (int i = 0; i < NT/4; ++i)
        gll16(wsrc + i*4096 + soff, (char*)wst[0] + i*4096 + w*1024);

    f32x4 acc[NT];
    #pragma unroll
    for (int ct = 0; ct < NT; ++ct) { float bv = bias[ct*16+r16]; acc[ct] = (f32x4){bv,bv,bv,bv}; }

    #pragma unroll
    for (int ks = 0; ks < 6; ++ks) {
        __syncthreads();     // chunk ks staged (vmcnt drained); prev-buf reads done
        if (ks < 5) {
            const char* s2 = wsrc + (size_t)(ks+1)*NT*1024;
            #pragma unroll
            for (int i = 0; i < NT/4; ++i)
                gll16(s2 + i*4096 + soff, (char*)wst[(ks+1)&1] + i*4096 + w*1024);
        }
        #pragma unroll
        for (int ct = 0; ct < NT; ++ct) {
            bf16x8 bb = *reinterpret_cast<const bf16x8*>(wst[ks&1] + ct*512 + lane*8);
            acc[ct] = __builtin_amdgcn_mfma_f32_16x16x32_bf16(aReg[ks], bb, acc[ct], 0, 0, 0);
        }
    }
    const int ldo = NT*16;
    #pragma unroll
    for (int ct = 0; ct < NT; ++ct)
        #pragma unroll
        for (int r = 0; r < 4; ++r)
            outp[(baserow + w16 + kg*4 + r)*ldo + ct*16 + r16] =
                __float2bfloat16(acc[ct][r] * scale);
}

// ---------------- K6: monolithic window attention (both sides + m + proj + fuse)
__global__ __launch_bounds__(256) void attn3_kernel(
    const __hip_bfloat16* __restrict__ Qglob,   // [2][73728][192]
    const __hip_bfloat16* __restrict__ KVglob,  // [2][73728][384]
    const __hip_bfloat16* __restrict__ xln_all, // [2][73728][192]
    const float* __restrict__ bias_glob,        // [6][64][64]
    const __hip_bfloat16* __restrict__ proj_f,  // frag-ordered
    const float* __restrict__ proj_b,
    const float* __restrict__ x_left, const float* __restrict__ x_right,
    float* __restrict__ out)
{
    __shared__ int tok[64];
    __shared__ unsigned short Vt[32*72];
    __shared__ unsigned short Pb[2][64*72];
    __shared__ unsigned short Tb[4][16*40];
    __shared__ float Gband[2][64][8];
    __shared__ float mstore[2][6][64];

    const int tid = threadIdx.x;
    const int lane = tid & 63, w = tid >> 6;
    const int r16 = lane & 15, kg = lane >> 4, w16 = w*16;
    const int widx = blockIdx.x;
    const int b = widx / NWIN, win = widx % NWIN;
    const int wi = win / NWX, wj = win % NWX;
    const bool edge_i = (wi == NWX-1), edge_j = (wj == NWX-1);

    if (tid < 64) {
        int p = tid;
        int rh = wi*8 + (p>>3), rw = wj*8 + (p&7);
        int i = rh + 4; if (i >= HH) i -= HH;
        int j = rw + 4; if (j >= WIMG) j -= WIMG;
        tok[p] = b*NTOK + i*WIMG + j;
    }
    __syncthreads();

    const int tokA = tok[w16 + r16];
    int tokB[4];
    #pragma unroll
    for (int ct = 0; ct < 4; ++ct) tokB[ct] = tok[ct*16 + r16];
    const int tokV = tok[tid >> 2];
    int tokC[4];
    #pragma unroll
    for (int r = 0; r < 4; ++r) tokC[r] = tok[w16 + 4*kg + r];

    f32x4 pacc[2][12];
    #pragma unroll
    for (int s = 0; s < 2; ++s)
        #pragma unroll
        for (int ct = 0; ct < 12; ++ct) pacc[s][ct] = (f32x4){0.f,0.f,0.f,0.f};

    for (int h = 0; h < 6; ++h) {
        __syncthreads();
        {
            float* gz = &Gband[0][0][0];
            #pragma unroll
            for (int z = 0; z < 4; ++z) gz[tid + z*256] = 0.f;
        }

        #pragma unroll
        for (int s = 0; s < 2; ++s) {
            const __hip_bfloat16* Qg  = Qglob  + (size_t)s*NSIDE_TOK*CC;
            const __hip_bfloat16* KVg = KVglob + (size_t)s*NSIDE_TOK*(2*CC);

            {
                int dgr = (tid & 3)*8;
                bf16x8 vv = *reinterpret_cast<const bf16x8*>(
                    KVg + (size_t)tokV*(2*CC) + CC + h*HD + dgr);
                #pragma unroll
                for (int jj = 0; jj < 8; ++jj)
                    Vt[(dgr+jj)*72 + (tid>>2)] = (unsigned short)vv[jj];
            }

            bf16x8 aQ = *reinterpret_cast<const bf16x8*>(
                Qg + (size_t)tokA*CC + h*HD + kg*8);
            f32x4 sv[4];
            #pragma unroll
            for (int ct = 0; ct < 4; ++ct) {
                bf16x8 bK = *reinterpret_cast<const bf16x8*>(
                    KVg + (size_t)tokB[ct]*(2*CC) + h*HD + kg*8);
                sv[ct] = __builtin_amdgcn_mfma_f32_16x16x32_bf16(
                    aQ, bK, (f32x4){0.f,0.f,0.f,0.f}, 0, 0, 0);
            }
            #pragma unroll
            for (int ct = 0; ct < 4; ++ct) {
                #pragma unroll
                for (int r = 0; r < 4; ++r) {
                    int q = w16 + 4*kg + r, k = ct*16 + r16;
                    float bm = bias_glob[h*4096 + q*64 + k];
                    int qy = q>>3, qx = q&7, ky = k>>3, kx = k&7;
                    bool msk = (edge_i && ((qy<4) != (ky<4))) ||
                               (edge_j && ((qx<4) != (kx<4)));
                    sv[ct][r] += bm + (msk ? -100.0f : 0.0f);
                }
            }
            float mx[4], sm[4];
            #pragma unroll
            for (int r = 0; r < 4; ++r) {
                mx[r] = fmaxf(fmaxf(sv[0][r], sv[1][r]), fmaxf(sv[2][r], sv[3][r]));
            }
            #pragma unroll
            for (int m = 1; m <= 8; m <<= 1)
                #pragma unroll
                for (int r = 0; r < 4; ++r) mx[r] = fmaxf(mx[r], __shfl_xor(mx[r], m, 64));
            #pragma unroll
            for (int r = 0; r < 4; ++r) sm[r] = 0.f;
            #pragma unroll
            for (int ct = 0; ct < 4; ++ct)
                #pragma unroll
                for (int r = 0; r < 4; ++r) {
                    sv[ct][r] = __expf(sv[ct][r] - mx[r]);
                    sm[r] += sv[ct][r];
                }
            #pragma unroll
            for (int m = 1; m <= 8; m <<= 1)
                #pragma unroll
                for (int r = 0; r < 4; ++r) sm[r] += __shfl_xor(sm[r], m, 64);
            #pragma unroll
            for (int r = 0; r < 4; ++r) sm[r] = 1.0f / sm[r];
            #pragma unroll
            for (int ct = 0; ct < 4; ++ct)
                #pragma unroll
                for (int r = 0; r < 4; ++r)
                    Pb[s][(w16 + 4*kg + r)*72 + ct*16 + r16] = f2bf(sv[ct][r]*sm[r]);

            __syncthreads();

            f32x4 ov[2];
            #pragma unroll
            for (int ht = 0; ht < 2; ++ht) ov[ht] = (f32x4){0.f,0.f,0.f,0.f};
            #pragma unroll
            for (int ks = 0; ks < 2; ++ks) {
                bf16x8 aP = *reinterpret_cast<const bf16x8*>(
                    Pb[s] + (w16+r16)*72 + ks*32 + kg*8);
                #pragma unroll
                for (int ht = 0; ht < 2; ++ht) {
                    bf16x8 bV = *reinterpret_cast<const bf16x8*>(
                        Vt + (ht*16 + r16)*72 + ks*32 + kg*8);
                    ov[ht] = __builtin_amdgcn_mfma_f32_16x16x32_bf16(aP, bV, ov[ht], 0, 0, 0);
                }
            }
            unsigned short* tb = &Tb[w][0];
            #pragma unroll
            for (int ht = 0; ht < 2; ++ht)
                #pragma unroll
                for (int r = 0; r < 4; ++r)
                    tb[(4*kg + r)*40 + ht*16 + r16] = f2bf(ov[ht][r]);
            __syncthreads();
            bf16x8 aO = *reinterpret_cast<const bf16x8*>(tb + r16*40 + kg*8);
            #pragma unroll
            for (int ct = 0; ct < 12; ++ct) {
                bf16x8 bP = *reinterpret_cast<const bf16x8*>(
                    proj_f + ((h*12 + ct)<<9) + lane*8);
                pacc[s][ct] = __builtin_amdgcn_mfma_f32_16x16x32_bf16(aO, bP, pacc[s][ct], 0, 0, 0);
            }
        } // sides

        __syncthreads();
        #pragma unroll
        for (int gi = 0; gi < 2; ++gi) {
            const unsigned short* PbA = Pb[gi];
            const unsigned short* PbB = Pb[1-gi];
            f32x4 gv[4];
            #pragma unroll
            for (int ct = 0; ct < 4; ++ct) gv[ct] = (f32x4){0.f,0.f,0.f,0.f};
            #pragma unroll
            for (int ks = 0; ks < 2; ++ks) {
                bf16x8 aG = *reinterpret_cast<const bf16x8*>(
                    PbA + (w16+r16)*72 + ks*32 + kg*8);
                #pragma unroll
                for (int ct = 0; ct < 4; ++ct) {
                    bf16x8 bG;
                    const unsigned short* pcol = PbB + (ks*32 + kg*8)*72 + ct*16 + r16;
                    #pragma unroll
                    for (int jj = 0; jj < 8; ++jj) bG[jj] = (short)pcol[jj*72];
                    gv[ct] = __builtin_amdgcn_mfma_f32_16x16x32_bf16(aG, bG, gv[ct], 0, 0, 0);
                }
            }
            #pragma unroll
            for (int ct = 0; ct < 4; ++ct)
                #pragma unroll
                for (int r = 0; r < 4; ++r) {
                    int row = w16 + 4*kg + r, col = ct*16 + r16;
                    int d = row - col + 2;
                    if (d >= 0 && d < 5) Gband[gi][col][d] = gv[ct][r];
                }
        }
        __syncthreads();
        if (tid < 128) {
            int s = tid >> 6, i = tid & 63;
            float s5 = Gband[s][i][0] + Gband[s][i][1] + Gband[s][i][2] +
                       Gband[s][i][3] + Gband[s][i][4];
            mstore[s][h][i] = tanhf(5.0f * s5);
        }
    } // heads

    __syncthreads();

    #pragma unroll
    for (int s = 0; s < 2; ++s) {
        const __hip_bfloat16* xw_s = xln_all + (size_t)s*NSIDE_TOK*CC;
        const float* xo_s = s ? x_right : x_left;
        float* out_s = out + (size_t)s*NSIDE_TOK*CC;
        #pragma unroll
        for (int ct = 0; ct < 12; ++ct) {
            int col = ct*16 + r16;
            int hh = ct >> 1;
            float pb_ = proj_b[col];
            #pragma unroll
            for (int r = 0; r < 4; ++r) {
                int q = w16 + 4*kg + r;
                size_t t = (size_t)tokC[r];
                float p = pacc[s][ct][r] + pb_;
                float m = mstore[s][hh][q];
                float xw = __bfloat162float(xw_s[t*CC + col]);
                float xo = xo_s[t*CC + col];
                out_s[t*CC + col] = xo + xw + (p - xw)*m;
            }
        }
    }
}

// ---------------- K7: fused MLP, LDS-staged double-buffered weights ---------
// 48 phases (24 fc1 + 24 fc2 12KB chunks), 1 syncthreads per phase, stage p+1
// overlaps compute p. A (16 tokens x K=192 per wave) lives in 24 VGPRs.
__global__ __launch_bounds__(256) void mlp_mfma_kernel(
    float* __restrict__ out,
    const float* __restrict__ g2, const float* __restrict__ b2,
    const __hip_bfloat16* __restrict__ W1f, const float* __restrict__ fc1_b,
    const __hip_bfloat16* __restrict__ W2f, const float* __restrict__ fc2_b)
{
    __shared__ unsigned short xt[64*200];     // 25600 B (LN transpose only)
    __shared__ unsigned short hbuf[64*72];    // 9216 B (wave-private rows)
    __shared__ unsigned short wst[2][6144];   // 2 x 12288 B weight staging
    const int tid  = threadIdx.x;
    const int lane = tid & 63;
    const int w    = tid >> 6;
    const int r16 = lane & 15, kg = lane >> 4, w16 = w*16;
    const size_t base = (size_t)blockIdx.x * 64 * CC;

    float ga = g2[lane], gb = g2[lane+64], gc = g2[lane+128];
    float ba = b2[lane], bbv = b2[lane+64], bc = b2[lane+128];

    for (int t = 0; t < 16; ++t) {
        int row = w16 + t;
        const float* src = out + base + (size_t)row*CC;
        float v0 = src[lane], v1 = src[lane+64], v2 = src[lane+128];
        float s = v0+v1+v2;
        float q = v0*v0 + v1*v1 + v2*v2;
        #pragma unroll
        for (int m = 32; m; m >>= 1) { s += __shfl_xor(s, m, 64); q += __shfl_xor(q, m, 64); }
        float mu = s * (1.0f/CC);
        float inv = rsqrtf(fmaxf(q*(1.0f/CC) - mu*mu, 0.0f) + EPS_);
        xt[row*200 + lane]     = f2bf((v0-mu)*inv*ga + ba);
        xt[row*200 + lane+64]  = f2bf((v1-mu)*inv*gb + bbv);
        xt[row*200 + lane+128] = f2bf((v2-mu)*inv*gc + bc);
    }
    __syncthreads();

    bf16x8 aReg[6];
    #pragma unroll
    for (int ks = 0; ks < 6; ++ks)
        aReg[ks] = *reinterpret_cast<const bf16x8*>(xt + (w16+r16)*200 + ks*32 + kg*8);

    const char* W1c = (const char*)W1f;   // 24 chunks x 12288 B
    const char* W2c = (const char*)W2f;   // 24 chunks x 12288 B
    const int soff = w*1024 + lane*16;
    const int doff = w*1024;

    // prologue: stage W1 chunk 0 -> wst[0]
    #pragma unroll
    for (int i = 0; i < 3; ++i)
        gll16(W1c + i*4096 + soff, (char*)wst[0] + i*4096 + doff);

    f32x4 acc2[12];
    #pragma unroll
    for (int i = 0; i < 12; ++i) acc2[i] = (f32x4){0.f,0.f,0.f,0.f};

    for (int cc = 0; cc < 12; ++cc) {
        f32x4 acc1[4];
        // ---- q0: fc1 cols cc*64..+31 from wst[0]; stage W1 chunk 2cc+1 -> wst[1]
        __syncthreads();
        {
            const char* s2 = W1c + (size_t)(2*cc+1)*12288;
            #pragma unroll
            for (int i = 0; i < 3; ++i)
                gll16(s2 + i*4096 + soff, (char*)wst[1] + i*4096 + doff);
        }
        #pragma unroll
        for (int c2 = 0; c2 < 2; ++c2) {
            float bv = fc1_b[cc*64 + c2*16 + r16];
            acc1[c2] = (f32x4){bv,bv,bv,bv};
        }
        #pragma unroll
        for (int ks = 0; ks < 6; ++ks)
            #pragma unroll
            for (int c2 = 0; c2 < 2; ++c2) {
                bf16x8 bw = *reinterpret_cast<const bf16x8*>(wst[0] + (ks*2+c2)*512 + lane*8);
                acc1[c2] = __builtin_amdgcn_mfma_f32_16x16x32_bf16(aReg[ks], bw, acc1[c2], 0, 0, 0);
            }
        // ---- q1: fc1 cols +32..63 from wst[1]; stage W2 chunk 2cc -> wst[0]
        __syncthreads();
        {
            const char* s2 = W2c + (size_t)(2*cc)*12288;
            #pragma unroll
            for (int i = 0; i < 3; ++i)
                gll16(s2 + i*4096 + soff, (char*)wst[0] + i*4096 + doff);
        }
        #pragma unroll
        for (int c2 = 0; c2 < 2; ++c2) {
            float bv = fc1_b[cc*64 + 32 + c2*16 + r16];
            acc1[2+c2] = (f32x4){bv,bv,bv,bv};
        }
        #pragma unroll
        for (int ks = 0; ks < 6; ++ks)
            #pragma unroll
            for (int c2 = 0; c2 < 2; ++c2) {
                bf16x8 bw = *reinterpret_cast<const bf16x8*>(wst[1] + (ks*2+c2)*512 + lane*8);
                acc1[2+c2] = __builtin_amdgcn_mfma_f32_16x16x32_bf16(aReg[ks], bw, acc1[2+c2], 0, 0, 0);
            }
        // GELU -> hbuf (wave-private rows)
        #pragma unroll
        for (int ct = 0; ct < 4; ++ct)
            #pragma unroll
            for (int r = 0; r < 4; ++r)
                hbuf[(w16 + kg*4 + r)*72 + ct*16 + r16] = f2bf(gelu_fast(acc1[ct][r]));
        // ---- q2: fc2 ks=0 from wst[0]; stage W2 chunk 2cc+1 -> wst[1]
        __syncthreads();
        {
            const char* s2 = W2c + (size_t)(2*cc+1)*12288;
            #pragma unroll
            for (int i = 0; i < 3; ++i)
                gll16(s2 + i*4096 + soff, (char*)wst[1] + i*4096 + doff);
        }
        {
            bf16x8 aP = *reinterpret_cast<const bf16x8*>(hbuf + (w16+r16)*72 + kg*8);
            #pragma unroll
            for (int ct = 0; ct < 12; ++ct) {
                bf16x8 bw = *reinterpret_cast<const bf16x8*>(wst[0] + ct*512 + lane*8);
                acc2[ct] = __builtin_amdgcn_mfma_f32_16x16x32_bf16(aP, bw, acc2[ct], 0, 0, 0);
            }
        }
        // ---- q3: fc2 ks=1 from wst[1]; stage W1 chunk 2cc+2 -> wst[0]
        __syncthreads();
        if (cc < 11) {
            const char* s2 = W1c + (size_t)(2*cc+2)*12288;
            #pragma unroll
            for (int i = 0; i < 3; ++i)
                gll16(s2 + i*4096 + soff, (char*)wst[0] + i*4096 + doff);
        }
        {
            bf16x8 aP = *reinterpret_cast<const bf16x8*>(hbuf + (w16+r16)*72 + 32 + kg*8);
            #pragma unroll
            for (int ct = 0; ct < 12; ++ct) {
                bf16x8 bw = *reinterpret_cast<const bf16x8*>(wst[1] + ct*512 + lane*8);
                acc2[ct] = __builtin_amdgcn_mfma_f32_16x16x32_bf16(aP, bw, acc2[ct], 0, 0, 0);
            }
        }
    }

    // epilogue: out += mlp + fc2_b
    #pragma unroll
    for (int ct = 0; ct < 12; ++ct) {
        int col = ct*16 + r16;
        float bv = fc2_b[col];
        #pragma unroll
        for (int r = 0; r < 4; ++r) {
            size_t idx = base + (size_t)(w16 + kg*4 + r)*CC + col;
            out[idx] = out[idx] + acc2[ct][r] + bv;
        }
    }
}

// ---------------- launch ----------------
extern "C" void kernel_launch(void* const* d_in, const int* in_sizes, int n_in,
                              void* d_out, int out_size, void* d_ws, size_t ws_size,
                              hipStream_t stream)
{
    (void)in_sizes; (void)n_in; (void)out_size; (void)ws_size;
    const float* x_left  = (const float*)d_in[0];
    const float* x_right = (const float*)d_in[1];
    const float* d_left  = (const float*)d_in[2];
    const float* d_right = (const float*)d_in[3];
    const float* n1g = (const float*)d_in[4];
    const float* n1b = (const float*)d_in[5];
    const float* q_w = (const float*)d_in[6];
    const float* q_b = (const float*)d_in[7];
    const float* kv_w = (const float*)d_in[8];
    const float* kv_b = (const float*)d_in[9];
    const float* proj_w = (const float*)d_in[10];
    const float* proj_b = (const float*)d_in[11];
    const float* bias_table = (const float*)d_in[12];
    const float* n2g = (const float*)d_in[13];
    const float* n2b = (const float*)d_in[14];
    const float* fc1_w = (const float*)d_in[15];
    const float* fc1_b = (const float*)d_in[16];
    const float* fc2_w = (const float*)d_in[17];
    const float* fc2_b = (const float*)d_in[18];
    float* out = (float*)d_out;

    char* ws = (char*)d_ws;
    __hip_bfloat16* xln_all  = (__hip_bfloat16*)(ws);                 // 56623104 B
    __hip_bfloat16* xsel_all = (__hip_bfloat16*)(ws + 56623104);      // 56623104 B
    __hip_bfloat16* Qg       = (__hip_bfloat16*)(ws + 56623104);      // aliases xsel (after KV gemm)
    __hip_bfloat16* KVg      = (__hip_bfloat16*)(ws + 113246208);     // 113246208 B
    __hip_bfloat16* q_wf     = (__hip_bfloat16*)(ws + 226492416);     // 73728 B
    __hip_bfloat16* kv_wf    = (__hip_bfloat16*)(ws + 226566144);     // 147456 B
    __hip_bfloat16* proj_f   = (__hip_bfloat16*)(ws + 226713600);     // 73728 B
    __hip_bfloat16* W1f      = (__hip_bfloat16*)(ws + 226787328);     // 294912 B
    __hip_bfloat16* W2f      = (__hip_bfloat16*)(ws + 227082240);     // 294912 B
    float*          bias_g   = (float*)         (ws + 227377152);     // 393216 B

    ln1_kernel<<<(2*NSIDE_TOK)/4, 256, 0, stream>>>(x_left, x_right, n1g, n1b, xln_all);

    conv_w_kernel<<<1728, 256, 0, stream>>>(q_w, kv_w, proj_w, fc1_w, fc2_w,
                                            q_wf, kv_wf, proj_f, W1f, W2f);
    bias_setup_kernel<<<96, 256, 0, stream>>>(bias_table, bias_g);

    gather_sel_kernel<<<(2*NSIDE_TOK*24)/256, 256, 0, stream>>>(
        xln_all, d_left, d_right, xsel_all);

    proj_gemm_kernel<24><<<(2*NSIDE_TOK)/64, 256, 0, stream>>>(
        xsel_all, kv_wf, kv_b, KVg, 1.0f);
    proj_gemm_kernel<12><<<(2*NSIDE_TOK)/64, 256, 0, stream>>>(
        xln_all, q_wf, q_b, Qg, 0.17677669529663687f);

    attn3_kernel<<<BWIN, 256, 0, stream>>>(
        Qg, KVg, xln_all, bias_g, proj_f, proj_b, x_left, x_right, out);

    mlp_mfma_kernel<<<(2*NSIDE_TOK)/64, 256, 0, stream>>>(
        out, n2g, n2b, W1f, fc1_b, W2f, fc2_b);
}

// Round 6
// 709.283 us; speedup vs baseline: 22.7048x; 1.0285x over previous
//
#include <hip/hip_runtime.h>
#include <hip/hip_bf16.h>

#define BB 2
#define HH 192
#define WIMG 192
#define CC 192
#define NHEADS 6
#define HD 32
#define NTOK (HH*WIMG)        // 36864 tokens per image
#define NWX 24                // windows per axis
#define NWIN 576
#define BWIN (BB*NWIN)        // 1152
#define MLPH 768
#define EPS_ 1e-5f
#define NSIDE_TOK (BB*NTOK)   // 73728 tokens per side

typedef __attribute__((ext_vector_type(8))) short bf16x8;
typedef __attribute__((ext_vector_type(4))) float f32x4;

#define GLOBAL_AS __attribute__((address_space(1)))
#define LDS_AS __attribute__((address_space(3)))
__device__ __forceinline__ void gll16(const void* g, void* l) {
    __builtin_amdgcn_global_load_lds((const GLOBAL_AS unsigned int*)g,
                                     (LDS_AS unsigned int*)l, 16, 0, 0);
}

__device__ __forceinline__ unsigned short f2bf(float f) {
    __hip_bfloat16 h = __float2bfloat16(f);
    return *reinterpret_cast<unsigned short*>(&h);
}
__device__ __forceinline__ float bfu(unsigned short u) {
    return __uint_as_float(((unsigned int)u) << 16);
}
// tanh-form GELU (max |err| vs exact ~3e-3; threshold 0.18)
__device__ __forceinline__ float gelu_fast(float x) {
    float z = 1.5957691216f*(x + 0.044715f*x*x*x);
    float e = __expf(z);
    float t = 1.0f - 2.0f/(e + 1.0f);
    return 0.5f*x*(1.0f + t);
}
// shifted-window token index for window (wi,wj), position p in [0,64)
__device__ __forceinline__ int tokof(int b, int wi, int wj, int p) {
    int rh = wi*8 + (p>>3), rw = wj*8 + (p&7);
    int i = rh + 4; if (i >= HH) i -= HH;
    int j = rw + 4; if (j >= WIMG) j -= WIMG;
    return b*NTOK + i*WIMG + j;
}

// ---------------- K1: LayerNorm1 -> bf16 ----------------
__global__ __launch_bounds__(256) void ln1_kernel(
    const float* __restrict__ xl, const float* __restrict__ xr,
    const float* __restrict__ g, const float* __restrict__ bta,
    __hip_bfloat16* __restrict__ xln_all)
{
    int token = blockIdx.x*4 + (threadIdx.x >> 6);
    int lane = threadIdx.x & 63;
    const float* src;
    __hip_bfloat16* dst;
    if (token < NSIDE_TOK) { src = xl + (size_t)token*CC; dst = xln_all + (size_t)token*CC; }
    else { int t2 = token - NSIDE_TOK; src = xr + (size_t)t2*CC; dst = xln_all + (size_t)token*CC; }
    float v0 = src[lane], v1 = src[lane+64], v2 = src[lane+128];
    float s = v0+v1+v2;
    float q = v0*v0 + v1*v1 + v2*v2;
    #pragma unroll
    for (int m = 32; m; m >>= 1) { s += __shfl_xor(s, m, 64); q += __shfl_xor(q, m, 64); }
    float mu = s * (1.0f/CC);
    float inv = rsqrtf(fmaxf(q*(1.0f/CC) - mu*mu, 0.0f) + EPS_);
    dst[lane]     = __float2bfloat16((v0-mu)*inv*g[lane]     + bta[lane]);
    dst[lane+64]  = __float2bfloat16((v1-mu)*inv*g[lane+64]  + bta[lane+64]);
    dst[lane+128] = __float2bfloat16((v2-mu)*inv*g[lane+128] + bta[lane+128]);
}

// ---------------- K2: epipolar gather (after LN) ----------------
__global__ __launch_bounds__(256) void gather_sel_kernel(
    const __hip_bfloat16* __restrict__ xln_all,
    const float* __restrict__ d_left, const float* __restrict__ d_right,
    __hip_bfloat16* __restrict__ xsel_all)
{
    int gid = blockIdx.x*256 + threadIdx.x;      // 2 * 73728 * 24
    int side = (gid >= NSIDE_TOK*24) ? 1 : 0;
    int rem = gid - side*NSIDE_TOK*24;
    int row = rem / 24, ch = rem - row*24;
    int j = row % WIMG;
    float d = side ? d_right[row] : d_left[row];
    int jj;
    if (!side) { float f = (float)j + 0.5f - d; f = fmaxf(f, 0.f); jj = (int)f; }
    else       { float f = (float)j + 0.5f + d; f = fminf(f, 191.f); jj = (int)f; }
    const __hip_bfloat16* srcb = xln_all + (side ? 0 : (size_t)NSIDE_TOK*CC);
    bf16x8 v = *reinterpret_cast<const bf16x8*>(srcb + (size_t)(row - j + jj)*CC + ch*8);
    *reinterpret_cast<bf16x8*>(xsel_all + (size_t)side*NSIDE_TOK*CC + (size_t)row*CC + ch*8) = v;
}

// ---------------- K3: convert weights to bf16 MFMA-FRAGMENT order ----------
__global__ __launch_bounds__(256) void conv_w_kernel(
    const float* __restrict__ q_w, const float* __restrict__ kv_w,
    const float* __restrict__ proj_w, const float* __restrict__ fc1_w,
    const float* __restrict__ fc2_w,
    __hip_bfloat16* __restrict__ q_wf, __hip_bfloat16* __restrict__ kv_wf,
    __hip_bfloat16* __restrict__ proj_f, __hip_bfloat16* __restrict__ W1f,
    __hip_bfloat16* __restrict__ W2f)
{
    int idx = blockIdx.x*256 + threadIdx.x;   // total 442368
    if (idx < 36864) {
        int j = idx & 7, lane = (idx>>3) & 63, fr = idx>>9;
        int ct = fr % 12, ks = fr / 12;
        int n = ct*16 + (lane&15), k = ks*32 + (lane>>4)*8 + j;
        q_wf[idx] = __float2bfloat16(q_w[(size_t)k*192 + n]);
    } else if (idx < 110592) {
        int i2 = idx - 36864;
        int j = i2 & 7, lane = (i2>>3) & 63, fr = i2>>9;
        int ct = fr % 24, ks = fr / 24;
        int n = ct*16 + (lane&15), k = ks*32 + (lane>>4)*8 + j;
        kv_wf[i2] = __float2bfloat16(kv_w[(size_t)k*384 + n]);
    } else if (idx < 147456) {
        int i2 = idx - 110592;
        int j = i2 & 7, lane = (i2>>3) & 63, fr = i2>>9;
        int ct = fr % 12, h = fr / 12;
        int n = ct*16 + (lane&15), k = h*32 + (lane>>4)*8 + j;
        proj_f[i2] = __float2bfloat16(proj_w[(size_t)k*192 + n]);
    } else if (idx < 294912) {
        // W1f: frag = (cc2*6 + ks)*2 + ct,  cc2 in [0,24), ct in [0,2)
        int i2 = idx - 147456;
        int j = i2 & 7, lane = (i2>>3) & 63, fr = i2>>9;
        int ct = fr & 1, ks = (fr>>1) % 6, cc2 = fr / 12;
        int n = cc2*32 + ct*16 + (lane&15), k = ks*32 + (lane>>4)*8 + j;
        W1f[i2] = __float2bfloat16(fc1_w[(size_t)k*MLPH + n]);
    } else {
        // W2f: frag = (cc*2+ks)*12+ct
        int i2 = idx - 294912;
        int j = i2 & 7, lane = (i2>>3) & 63, fr = i2>>9;
        int ct = fr % 12, ks = (fr/12) % 2, cc = fr / 24;
        int n = ct*16 + (lane&15), k = cc*64 + ks*32 + (lane>>4)*8 + j;
        W2f[i2] = __float2bfloat16(fc2_w[(size_t)k*192 + n]);
    }
}

// ---------------- K4: per-head rel-pos bias matrix [6][64][64] f32 ----------
__global__ __launch_bounds__(256) void bias_setup_kernel(
    const float* __restrict__ table, float* __restrict__ bias_glob)
{
    int idx = blockIdx.x*256 + threadIdx.x;   // 24576
    int h = idx >> 12, rem = idx & 4095;
    int q = rem >> 6, k = rem & 63;
    int qy = q>>3, qx = q&7, ky = k>>3, kx = k&7;
    int ridx = (qy-ky+7)*15 + (qx-kx+7);
    bias_glob[idx] = table[ridx*NHEADS + h];
}

// ---------------- K5: bf16 MFMA projection GEMM (A in regs, W staged in LDS)
template<int NT>
__global__ __launch_bounds__(256) void proj_gemm_kernel(
    const __hip_bfloat16* __restrict__ in, const __hip_bfloat16* __restrict__ Wf,
    const float* __restrict__ bias, __hip_bfloat16* __restrict__ outp, float scale)
{
    __shared__ unsigned short wst[2][NT*512];
    const int tid = threadIdx.x, lane = tid & 63, w = tid >> 6;
    const int r16 = lane & 15, kg = lane >> 4, w16 = w*16;
    const size_t baserow = (size_t)blockIdx.x * 64;
    const size_t row = baserow + w16 + r16;

    bf16x8 aReg[6];
    #pragma unroll
    for (int ks = 0; ks < 6; ++ks)
        aReg[ks] = *reinterpret_cast<const bf16x8*>(in + row*CC + ks*32 + kg*8);

    const char* wsrc = (const char*)Wf;
    const int soff = w*1024 + lane*16;
    #pragma unroll
    for (int i = 0; i < NT/4; ++i)
        gll16(wsrc + i*4096 + soff, (char*)wst[0] + i*4096 + w*1024);

    f32x4 acc[NT];
    #pragma unroll
    for (int ct = 0; ct < NT; ++ct) { float bv = bias[ct*16+r16]; acc[ct] = (f32x4){bv,bv,bv,bv}; }

    #pragma unroll
    for (int ks = 0; ks < 6; ++ks) {
        __syncthreads();
        if (ks < 5) {
            const char* s2 = wsrc + (size_t)(ks+1)*NT*1024;
            #pragma unroll
            for (int i = 0; i < NT/4; ++i)
                gll16(s2 + i*4096 + soff, (char*)wst[(ks+1)&1] + i*4096 + w*1024);
        }
        #pragma unroll
        for (int ct = 0; ct < NT; ++ct) {
            bf16x8 bb = *reinterpret_cast<const bf16x8*>(wst[ks&1] + ct*512 + lane*8);
            acc[ct] = __builtin_amdgcn_mfma_f32_16x16x32_bf16(aReg[ks], bb, acc[ct], 0, 0, 0);
        }
    }
    const int ldo = NT*16;
    #pragma unroll
    for (int ct = 0; ct < NT; ++ct)
        #pragma unroll
        for (int r = 0; r < 4; ++r)
            outp[(baserow + w16 + kg*4 + r)*ldo + ct*16 + r16] =
                __float2bfloat16(acc[ct][r] * scale);
}

// ---------------- K6: window attention P+O — ZERO barriers ------------------
// grid 2304 = (side, window); 2 waves; wave w does heads {w, w+2, w+4}.
// All LDS wave-private; P also stored to Pg (global) for m_kernel; O (pre-proj)
// to Og.
__global__ __launch_bounds__(128) void attn_p_kernel(
    const __hip_bfloat16* __restrict__ Qglob,   // [2][73728][192]
    const __hip_bfloat16* __restrict__ KVglob,  // [2][73728][384]
    const float* __restrict__ bias_glob,        // [6][64][64]
    unsigned short* __restrict__ Pg,            // [1152][6][2][4096]
    __hip_bfloat16* __restrict__ Og)            // [2*1152*64][192]
{
    __shared__ unsigned short Pl[2][64*72];
    __shared__ unsigned short Vl[2][32*72];
    const int tid = threadIdx.x, lane = tid & 63, w = tid >> 6;
    const int r16 = lane & 15, kg = lane >> 4;
    const int bid = blockIdx.x;
    const int s = bid / BWIN, wd = bid % BWIN;
    const int b = wd / NWIN, win = wd % NWIN;
    const int wi = win / NWX, wj = win % NWX;
    const bool edge_i = (wi == NWX-1), edge_j = (wj == NWX-1);

    const __hip_bfloat16* Qs  = Qglob  + (size_t)s*NSIDE_TOK*CC;
    const __hip_bfloat16* KVs = KVglob + (size_t)s*NSIDE_TOK*(2*CC);

    int tokQ[4];
    #pragma unroll
    for (int mi = 0; mi < 4; ++mi) tokQ[mi] = tokof(b, wi, wj, mi*16 + r16);
    const int tokV = tokof(b, wi, wj, lane);

    unsigned short* P = Pl[w];
    unsigned short* V = Vl[w];

    for (int r = 0; r < 3; ++r) {
        const int h = r*2 + w;
        // ---- stage V^T (wave-private, no barrier)
        bf16x8 vv[4];
        #pragma unroll
        for (int dg = 0; dg < 4; ++dg)
            vv[dg] = *reinterpret_cast<const bf16x8*>(
                KVs + (size_t)tokV*(2*CC) + CC + h*HD + dg*8);
        #pragma unroll
        for (int dg = 0; dg < 4; ++dg)
            #pragma unroll
            for (int jj = 0; jj < 8; ++jj)
                V[(dg*8+jj)*72 + lane] = (unsigned short)vv[dg][jj];

        // ---- S = Q K^T  (full 64x64 per wave)
        bf16x8 aQ[4], bK[4];
        #pragma unroll
        for (int mi = 0; mi < 4; ++mi)
            aQ[mi] = *reinterpret_cast<const bf16x8*>(
                Qs + (size_t)tokQ[mi]*CC + h*HD + kg*8);
        #pragma unroll
        for (int ni = 0; ni < 4; ++ni)
            bK[ni] = *reinterpret_cast<const bf16x8*>(
                KVs + (size_t)tokQ[ni]*(2*CC) + h*HD + kg*8);
        f32x4 S[4][4];
        #pragma unroll
        for (int mi = 0; mi < 4; ++mi)
            #pragma unroll
            for (int ni = 0; ni < 4; ++ni)
                S[mi][ni] = __builtin_amdgcn_mfma_f32_16x16x32_bf16(
                    aQ[mi], bK[ni], (f32x4){0.f,0.f,0.f,0.f}, 0, 0, 0);

        // ---- bias + shift mask
        #pragma unroll
        for (int mi = 0; mi < 4; ++mi)
            #pragma unroll
            for (int ni = 0; ni < 4; ++ni)
                #pragma unroll
                for (int rr = 0; rr < 4; ++rr) {
                    int q = mi*16 + kg*4 + rr, k = ni*16 + r16;
                    float bm = bias_glob[h*4096 + q*64 + k];
                    int qy = q>>3, qx = q&7, ky = k>>3, kx = k&7;
                    bool msk = (edge_i && ((qy<4) != (ky<4))) ||
                               (edge_j && ((qx<4) != (kx<4)));
                    S[mi][ni][rr] += bm + (msk ? -100.0f : 0.0f);
                }

        // ---- softmax over k (regs over ni, shfl over 16 lanes)
        float mx[4][4], sm[4][4];
        #pragma unroll
        for (int mi = 0; mi < 4; ++mi)
            #pragma unroll
            for (int rr = 0; rr < 4; ++rr)
                mx[mi][rr] = fmaxf(fmaxf(S[mi][0][rr], S[mi][1][rr]),
                                   fmaxf(S[mi][2][rr], S[mi][3][rr]));
        #pragma unroll
        for (int m = 1; m <= 8; m <<= 1)
            #pragma unroll
            for (int mi = 0; mi < 4; ++mi)
                #pragma unroll
                for (int rr = 0; rr < 4; ++rr)
                    mx[mi][rr] = fmaxf(mx[mi][rr], __shfl_xor(mx[mi][rr], m, 64));
        #pragma unroll
        for (int mi = 0; mi < 4; ++mi)
            #pragma unroll
            for (int rr = 0; rr < 4; ++rr) sm[mi][rr] = 0.f;
        #pragma unroll
        for (int mi = 0; mi < 4; ++mi)
            #pragma unroll
            for (int ni = 0; ni < 4; ++ni)
                #pragma unroll
                for (int rr = 0; rr < 4; ++rr) {
                    S[mi][ni][rr] = __expf(S[mi][ni][rr] - mx[mi][rr]);
                    sm[mi][rr] += S[mi][ni][rr];
                }
        #pragma unroll
        for (int m = 1; m <= 8; m <<= 1)
            #pragma unroll
            for (int mi = 0; mi < 4; ++mi)
                #pragma unroll
                for (int rr = 0; rr < 4; ++rr)
                    sm[mi][rr] += __shfl_xor(sm[mi][rr], m, 64);
        #pragma unroll
        for (int mi = 0; mi < 4; ++mi)
            #pragma unroll
            for (int rr = 0; rr < 4; ++rr) sm[mi][rr] = 1.0f / sm[mi][rr];

        // ---- P -> LDS (wave-private)
        #pragma unroll
        for (int mi = 0; mi < 4; ++mi)
            #pragma unroll
            for (int ni = 0; ni < 4; ++ni)
                #pragma unroll
                for (int rr = 0; rr < 4; ++rr)
                    P[(mi*16 + kg*4 + rr)*72 + ni*16 + r16] =
                        f2bf(S[mi][ni][rr] * sm[mi][rr]);

        // ---- P -> global (coalesced via LDS re-read)
        {
            const size_t pbase = ((size_t)(wd*NHEADS + h)*2 + s) * 4096;
            #pragma unroll
            for (int it = 0; it < 8; ++it) {
                int c = it*64 + lane;           // 512 chunks of 8 shorts
                int q = c >> 3, k8 = (c & 7)*8;
                bf16x8 pv = *reinterpret_cast<const bf16x8*>(P + q*72 + k8);
                *reinterpret_cast<bf16x8*>(Pg + pbase + c*8) = pv;
            }
        }

        // ---- PV (own P, own V^T)
        f32x4 O[4][2];
        #pragma unroll
        for (int mi = 0; mi < 4; ++mi)
            #pragma unroll
            for (int dt = 0; dt < 2; ++dt) O[mi][dt] = (f32x4){0.f,0.f,0.f,0.f};
        #pragma unroll
        for (int ks = 0; ks < 2; ++ks) {
            bf16x8 aP[4], bV[2];
            #pragma unroll
            for (int mi = 0; mi < 4; ++mi)
                aP[mi] = *reinterpret_cast<const bf16x8*>(
                    P + (mi*16 + r16)*72 + ks*32 + kg*8);
            #pragma unroll
            for (int dt = 0; dt < 2; ++dt)
                bV[dt] = *reinterpret_cast<const bf16x8*>(
                    V + (dt*16 + r16)*72 + ks*32 + kg*8);
            #pragma unroll
            for (int mi = 0; mi < 4; ++mi)
                #pragma unroll
                for (int dt = 0; dt < 2; ++dt)
                    O[mi][dt] = __builtin_amdgcn_mfma_f32_16x16x32_bf16(
                        aP[mi], bV[dt], O[mi][dt], 0, 0, 0);
        }
        // ---- O store (window-ordered, scatter-free rows)
        {
            __hip_bfloat16* ob = Og + ((size_t)(s*BWIN + wd)*64)*CC + h*HD;
            #pragma unroll
            for (int mi = 0; mi < 4; ++mi)
                #pragma unroll
                for (int dt = 0; dt < 2; ++dt)
                    #pragma unroll
                    for (int rr = 0; rr < 4; ++rr)
                        ob[(size_t)(mi*16 + kg*4 + rr)*CC + dt*16 + r16] =
                            __float2bfloat16(O[mi][dt][rr]);
        }
    }
}

// ---------------- K7: m = tanh(5 * banded P0·P1) ----------------------------
// grid 1152*6 = (window, head), 128 threads: t = (sIdx<<6)|i
__global__ __launch_bounds__(128) void m_kernel(
    const unsigned short* __restrict__ Pg, float* __restrict__ mg)
{
    __shared__ unsigned short Pl[2][64*66];
    const int bid = blockIdx.x;
    const int wd = bid / NHEADS, h = bid % NHEADS;
    const int t = threadIdx.x;
    const size_t base = ((size_t)(wd*NHEADS + h)*2) * 4096;

    // copy-in 8192 shorts as 4096 u32 (coalesced)
    #pragma unroll
    for (int it = 0; it < 32; ++it) {
        int c = it*128 + t;
        int side = c >> 11, rem = c & 2047;
        int q = rem >> 5, k2 = rem & 31;
        unsigned int v = *reinterpret_cast<const unsigned int*>(
            Pg + base + side*4096 + q*64 + k2*2);
        *reinterpret_cast<unsigned int*>(&Pl[side][q*66 + k2*2]) = v;
    }
    __syncthreads();

    const int sIdx = t >> 6, i = t & 63;
    const unsigned short* Pa = Pl[sIdx];
    const unsigned short* Pb = Pl[sIdx ^ 1];
    const int s0 = (i >= 2) ? -2 : -i;
    const int s1 = (i <= 61) ? 2 : 63 - i;
    float acc = 0.f;
    for (int k = 0; k < 64; k += 2) {
        float pb0 = bfu(Pb[k*66 + i]);
        float pb1 = bfu(Pb[(k+1)*66 + i]);
        float a0 = 0.f, a1 = 0.f;
        for (int ss = s0; ss <= s1; ++ss) {
            unsigned int pr = *reinterpret_cast<const unsigned int*>(
                &Pa[(i+ss)*66 + k]);
            a0 += bfu((unsigned short)(pr & 0xffff));
            a1 += bfu((unsigned short)(pr >> 16));
        }
        acc += a0*pb0 + a1*pb1;
    }
    float e = __expf(10.0f * acc);           // tanh(5a), a >= 0
    mg[((size_t)(sIdx*BWIN + wd)*NHEADS + h)*64 + i] = 1.0f - 2.0f/(e + 1.0f);
}

// ---------------- K8: proj + fuse + window reverse + residual ---------------
// grid 2304 = (side, window), 256 threads
__global__ __launch_bounds__(256) void projfuse_kernel(
    const __hip_bfloat16* __restrict__ Og,
    const __hip_bfloat16* __restrict__ proj_f,
    const float* __restrict__ proj_b,
    const float* __restrict__ mg,
    const __hip_bfloat16* __restrict__ xln_all,
    const float* __restrict__ x_left, const float* __restrict__ x_right,
    float* __restrict__ out)
{
    __shared__ unsigned short wst[2][12*512];
    const int tid = threadIdx.x, lane = tid & 63, w = tid >> 6;
    const int r16 = lane & 15, kg = lane >> 4, w16 = w*16;
    const int bid = blockIdx.x;
    const int s = bid / BWIN, wd = bid % BWIN;
    const int b = wd / NWIN, win = wd % NWIN;
    const int wi = win / NWX, wj = win % NWX;

    const size_t orow = (size_t)(s*BWIN + wd)*64 + w16 + r16;
    bf16x8 aReg[6];
    #pragma unroll
    for (int ks = 0; ks < 6; ++ks)
        aReg[ks] = *reinterpret_cast<const bf16x8*>(Og + orow*CC + ks*32 + kg*8);

    const char* wsrc = (const char*)proj_f;
    const int soff = w*1024 + lane*16;
    #pragma unroll
    for (int i = 0; i < 3; ++i)
        gll16(wsrc + i*4096 + soff, (char*)wst[0] + i*4096 + w*1024);

    f32x4 acc[12];
    #pragma unroll
    for (int ct = 0; ct < 12; ++ct) { float bv = proj_b[ct*16+r16]; acc[ct] = (f32x4){bv,bv,bv,bv}; }

    #pragma unroll
    for (int ks = 0; ks < 6; ++ks) {
        __syncthreads();
        if (ks < 5) {
            const char* s2 = wsrc + (size_t)(ks+1)*12288;
            #pragma unroll
            for (int i = 0; i < 3; ++i)
                gll16(s2 + i*4096 + soff, (char*)wst[(ks+1)&1] + i*4096 + w*1024);
        }
        #pragma unroll
        for (int ct = 0; ct < 12; ++ct) {
            bf16x8 bb = *reinterpret_cast<const bf16x8*>(wst[ks&1] + ct*512 + lane*8);
            acc[ct] = __builtin_amdgcn_mfma_f32_16x16x32_bf16(aReg[ks], bb, acc[ct], 0, 0, 0);
        }
    }

    // epilogue: fuse + window reverse + residual
    int tk[4];
    #pragma unroll
    for (int rr = 0; rr < 4; ++rr) tk[rr] = tokof(b, wi, wj, w16 + kg*4 + rr);
    const float* xo_s = s ? x_right : x_left;
    const __hip_bfloat16* xw_s = xln_all + (size_t)s*NSIDE_TOK*CC;
    float* out_s = out + (size_t)s*NSIDE_TOK*CC;
    const float* mrow = mg + (size_t)(s*BWIN + wd)*NHEADS*64;
    #pragma unroll
    for (int ct = 0; ct < 12; ++ct) {
        int col = ct*16 + r16;
        int h = ct >> 1;
        #pragma unroll
        for (int rr = 0; rr < 4; ++rr) {
            int q = w16 + kg*4 + rr;
            size_t tt = (size_t)tk[rr];
            float m = mrow[h*64 + q];
            float xw = __bfloat162float(xw_s[tt*CC + col]);
            float p = acc[ct][rr];
            out_s[tt*CC + col] = xo_s[tt*CC + col] + xw + (p - xw)*m;
        }
    }
}

// ---------------- K9: fused MLP, LDS-staged double-buffered weights ---------
__global__ __launch_bounds__(256) void mlp_mfma_kernel(
    float* __restrict__ out,
    const float* __restrict__ g2, const float* __restrict__ b2,
    const __hip_bfloat16* __restrict__ W1f, const float* __restrict__ fc1_b,
    const __hip_bfloat16* __restrict__ W2f, const float* __restrict__ fc2_b)
{
    __shared__ unsigned short xt[64*200];
    __shared__ unsigned short hbuf[64*72];
    __shared__ unsigned short wst[2][6144];
    const int tid  = threadIdx.x;
    const int lane = tid & 63;
    const int w    = tid >> 6;
    const int r16 = lane & 15, kg = lane >> 4, w16 = w*16;
    const size_t base = (size_t)blockIdx.x * 64 * CC;

    float ga = g2[lane], gb = g2[lane+64], gc = g2[lane+128];
    float ba = b2[lane], bbv = b2[lane+64], bc = b2[lane+128];

    for (int t = 0; t < 16; ++t) {
        int row = w16 + t;
        const float* src = out + base + (size_t)row*CC;
        float v0 = src[lane], v1 = src[lane+64], v2 = src[lane+128];
        float s = v0+v1+v2;
        float q = v0*v0 + v1*v1 + v2*v2;
        #pragma unroll
        for (int m = 32; m; m >>= 1) { s += __shfl_xor(s, m, 64); q += __shfl_xor(q, m, 64); }
        float mu = s * (1.0f/CC);
        float inv = rsqrtf(fmaxf(q*(1.0f/CC) - mu*mu, 0.0f) + EPS_);
        xt[row*200 + lane]     = f2bf((v0-mu)*inv*ga + ba);
        xt[row*200 + lane+64]  = f2bf((v1-mu)*inv*gb + bbv);
        xt[row*200 + lane+128] = f2bf((v2-mu)*inv*gc + bc);
    }
    __syncthreads();

    bf16x8 aReg[6];
    #pragma unroll
    for (int ks = 0; ks < 6; ++ks)
        aReg[ks] = *reinterpret_cast<const bf16x8*>(xt + (w16+r16)*200 + ks*32 + kg*8);

    const char* W1c = (const char*)W1f;
    const char* W2c = (const char*)W2f;
    const int soff = w*1024 + lane*16;
    const int doff = w*1024;

    #pragma unroll
    for (int i = 0; i < 3; ++i)
        gll16(W1c + i*4096 + soff, (char*)wst[0] + i*4096 + doff);

    f32x4 acc2[12];
    #pragma unroll
    for (int i = 0; i < 12; ++i) acc2[i] = (f32x4){0.f,0.f,0.f,0.f};

    for (int cc = 0; cc < 12; ++cc) {
        f32x4 acc1[4];
        __syncthreads();
        {
            const char* s2 = W1c + (size_t)(2*cc+1)*12288;
            #pragma unroll
            for (int i = 0; i < 3; ++i)
                gll16(s2 + i*4096 + soff, (char*)wst[1] + i*4096 + doff);
        }
        #pragma unroll
        for (int c2 = 0; c2 < 2; ++c2) {
            float bv = fc1_b[cc*64 + c2*16 + r16];
            acc1[c2] = (f32x4){bv,bv,bv,bv};
        }
        #pragma unroll
        for (int ks = 0; ks < 6; ++ks)
            #pragma unroll
            for (int c2 = 0; c2 < 2; ++c2) {
                bf16x8 bw = *reinterpret_cast<const bf16x8*>(wst[0] + (ks*2+c2)*512 + lane*8);
                acc1[c2] = __builtin_amdgcn_mfma_f32_16x16x32_bf16(aReg[ks], bw, acc1[c2], 0, 0, 0);
            }
        __syncthreads();
        {
            const char* s2 = W2c + (size_t)(2*cc)*12288;
            #pragma unroll
            for (int i = 0; i < 3; ++i)
                gll16(s2 + i*4096 + soff, (char*)wst[0] + i*4096 + doff);
        }
        #pragma unroll
        for (int c2 = 0; c2 < 2; ++c2) {
            float bv = fc1_b[cc*64 + 32 + c2*16 + r16];
            acc1[2+c2] = (f32x4){bv,bv,bv,bv};
        }
        #pragma unroll
        for (int ks = 0; ks < 6; ++ks)
            #pragma unroll
            for (int c2 = 0; c2 < 2; ++c2) {
                bf16x8 bw = *reinterpret_cast<const bf16x8*>(wst[1] + (ks*2+c2)*512 + lane*8);
                acc1[2+c2] = __builtin_amdgcn_mfma_f32_16x16x32_bf16(aReg[ks], bw, acc1[2+c2], 0, 0, 0);
            }
        #pragma unroll
        for (int ct = 0; ct < 4; ++ct)
            #pragma unroll
            for (int r = 0; r < 4; ++r)
                hbuf[(w16 + kg*4 + r)*72 + ct*16 + r16] = f2bf(gelu_fast(acc1[ct][r]));
        __syncthreads();
        {
            const char* s2 = W2c + (size_t)(2*cc+1)*12288;
            #pragma unroll
            for (int i = 0; i < 3; ++i)
                gll16(s2 + i*4096 + soff, (char*)wst[1] + i*4096 + doff);
        }
        {
            bf16x8 aP = *reinterpret_cast<const bf16x8*>(hbuf + (w16+r16)*72 + kg*8);
            #pragma unroll
            for (int ct = 0; ct < 12; ++ct) {
                bf16x8 bw = *reinterpret_cast<const bf16x8*>(wst[0] + ct*512 + lane*8);
                acc2[ct] = __builtin_amdgcn_mfma_f32_16x16x32_bf16(aP, bw, acc2[ct], 0, 0, 0);
            }
        }
        __syncthreads();
        if (cc < 11) {
            const char* s2 = W1c + (size_t)(2*cc+2)*12288;
            #pragma unroll
            for (int i = 0; i < 3; ++i)
                gll16(s2 + i*4096 + soff, (char*)wst[0] + i*4096 + doff);
        }
        {
            bf16x8 aP = *reinterpret_cast<const bf16x8*>(hbuf + (w16+r16)*72 + 32 + kg*8);
            #pragma unroll
            for (int ct = 0; ct < 12; ++ct) {
                bf16x8 bw = *reinterpret_cast<const bf16x8*>(wst[1] + ct*512 + lane*8);
                acc2[ct] = __builtin_amdgcn_mfma_f32_16x16x32_bf16(aP, bw, acc2[ct], 0, 0, 0);
            }
        }
    }

    #pragma unroll
    for (int ct = 0; ct < 12; ++ct) {
        int col = ct*16 + r16;
        float bv = fc2_b[col];
        #pragma unroll
        for (int r = 0; r < 4; ++r) {
            size_t idx = base + (size_t)(w16 + kg*4 + r)*CC + col;
            out[idx] = out[idx] + acc2[ct][r] + bv;
        }
    }
}

// ---------------- launch ----------------
extern "C" void kernel_launch(void* const* d_in, const int* in_sizes, int n_in,
                              void* d_out, int out_size, void* d_ws, size_t ws_size,
                              hipStream_t stream)
{
    (void)in_sizes; (void)n_in; (void)out_size; (void)ws_size;
    const float* x_left  = (const float*)d_in[0];
    const float* x_right = (const float*)d_in[1];
    const float* d_left  = (const float*)d_in[2];
    const float* d_right = (const float*)d_in[3];
    const float* n1g = (const float*)d_in[4];
    const float* n1b = (const float*)d_in[5];
    const float* q_w = (const float*)d_in[6];
    const float* q_b = (const float*)d_in[7];
    const float* kv_w = (const float*)d_in[8];
    const float* kv_b = (const float*)d_in[9];
    const float* proj_w = (const float*)d_in[10];
    const float* proj_b = (const float*)d_in[11];
    const float* bias_table = (const float*)d_in[12];
    const float* n2g = (const float*)d_in[13];
    const float* n2b = (const float*)d_in[14];
    const float* fc1_w = (const float*)d_in[15];
    const float* fc1_b = (const float*)d_in[16];
    const float* fc2_w = (const float*)d_in[17];
    const float* fc2_b = (const float*)d_in[18];
    float* out = (float*)d_out;

    char* ws = (char*)d_ws;
    __hip_bfloat16* xln_all  = (__hip_bfloat16*)(ws);                 // 56623104 B
    __hip_bfloat16* xsel_all = (__hip_bfloat16*)(ws + 56623104);      // 56623104 B
    __hip_bfloat16* Qg       = (__hip_bfloat16*)(ws + 56623104);      // aliases xsel
    __hip_bfloat16* KVg      = (__hip_bfloat16*)(ws + 113246208);     // 113246208 B
    __hip_bfloat16* q_wf     = (__hip_bfloat16*)(ws + 226492416);     // 73728 B
    __hip_bfloat16* kv_wf    = (__hip_bfloat16*)(ws + 226566144);     // 147456 B
    __hip_bfloat16* proj_f   = (__hip_bfloat16*)(ws + 226713600);     // 73728 B
    __hip_bfloat16* W1f      = (__hip_bfloat16*)(ws + 226787328);     // 294912 B
    __hip_bfloat16* W2f      = (__hip_bfloat16*)(ws + 227082240);     // 294912 B
    float*          bias_g   = (float*)         (ws + 227377152);     // 393216 B
    __hip_bfloat16* Og       = (__hip_bfloat16*)(ws + 227770368);     // 56623104 B
    float*          mg       = (float*)         (ws + 284393472);     // 3538944 B
    // Pg scratch lives in d_out (113246208 B, exact fit); overwritten by
    // projfuse_kernel AFTER m_kernel has consumed it.
    unsigned short* Pg       = (unsigned short*)d_out;

    ln1_kernel<<<(2*NSIDE_TOK)/4, 256, 0, stream>>>(x_left, x_right, n1g, n1b, xln_all);

    conv_w_kernel<<<1728, 256, 0, stream>>>(q_w, kv_w, proj_w, fc1_w, fc2_w,
                                            q_wf, kv_wf, proj_f, W1f, W2f);
    bias_setup_kernel<<<96, 256, 0, stream>>>(bias_table, bias_g);

    gather_sel_kernel<<<(2*NSIDE_TOK*24)/256, 256, 0, stream>>>(
        xln_all, d_left, d_right, xsel_all);

    proj_gemm_kernel<24><<<(2*NSIDE_TOK)/64, 256, 0, stream>>>(
        xsel_all, kv_wf, kv_b, KVg, 1.0f);
    proj_gemm_kernel<12><<<(2*NSIDE_TOK)/64, 256, 0, stream>>>(
        xln_all, q_wf, q_b, Qg, 0.17677669529663687f);

    attn_p_kernel<<<2*BWIN, 128, 0, stream>>>(Qg, KVg, bias_g, Pg, Og);
    m_kernel<<<BWIN*NHEADS, 128, 0, stream>>>(Pg, mg);
    projfuse_kernel<<<2*BWIN, 256, 0, stream>>>(
        Og, proj_f, proj_b, mg, xln_all, x_left, x_right, out);

    mlp_mfma_kernel<<<(2*NSIDE_TOK)/64, 256, 0, stream>>>(
        out, n2g, n2b, W1f, fc1_b, W2f, fc2_b);
}

// Round 10
// 536.281 us; speedup vs baseline: 30.0293x; 1.3226x over previous
//
#include <hip/hip_runtime.h>
#include <hip/hip_bf16.h>

#define BB 2
#define HH 192
#define WIMG 192
#define CC 192
#define NHEADS 6
#define HD 32
#define NTOK (HH*WIMG)        // 36864 tokens per image
#define NWX 24                // windows per axis
#define NWIN 576
#define BWIN (BB*NWIN)        // 1152
#define MLPH 768
#define EPS_ 1e-5f
#define NSIDE_TOK (BB*NTOK)   // 73728 tokens per side

typedef __attribute__((ext_vector_type(8))) short bf16x8;
typedef __attribute__((ext_vector_type(4))) float f32x4;

#define GLOBAL_AS __attribute__((address_space(1)))
#define LDS_AS __attribute__((address_space(3)))
__device__ __forceinline__ void gll16(const void* g, void* l) {
    __builtin_amdgcn_global_load_lds((const GLOBAL_AS unsigned int*)g,
                                     (LDS_AS unsigned int*)l, 16, 0, 0);
}

__device__ __forceinline__ unsigned short f2bf(float f) {
    __hip_bfloat16 h = __float2bfloat16(f);
    return *reinterpret_cast<unsigned short*>(&h);
}
__device__ __forceinline__ float bfu(unsigned short u) {
    return __uint_as_float(((unsigned int)u) << 16);
}
// tanh-form GELU (max |err| vs exact ~3e-3; threshold 0.18)
__device__ __forceinline__ float gelu_fast(float x) {
    float z = 1.5957691216f*(x + 0.044715f*x*x*x);
    float e = __expf(z);
    float t = 1.0f - 2.0f/(e + 1.0f);
    return 0.5f*x*(1.0f + t);
}
// shifted-window token index for window (wi,wj), position p in [0,64)
__device__ __forceinline__ int tokof(int b, int wi, int wj, int p) {
    int rh = wi*8 + (p>>3), rw = wj*8 + (p&7);
    int i = rh + 4; if (i >= HH) i -= HH;
    int j = rw + 4; if (j >= WIMG) j -= WIMG;
    return b*NTOK + i*WIMG + j;
}

// ---------------- K1: LayerNorm1 -> bf16 ----------------
__global__ __launch_bounds__(256) void ln1_kernel(
    const float* __restrict__ xl, const float* __restrict__ xr,
    const float* __restrict__ g, const float* __restrict__ bta,
    __hip_bfloat16* __restrict__ xln_all)
{
    int token = blockIdx.x*4 + (threadIdx.x >> 6);
    int lane = threadIdx.x & 63;
    const float* src;
    __hip_bfloat16* dst;
    if (token < NSIDE_TOK) { src = xl + (size_t)token*CC; dst = xln_all + (size_t)token*CC; }
    else { int t2 = token - NSIDE_TOK; src = xr + (size_t)t2*CC; dst = xln_all + (size_t)token*CC; }
    float v0 = src[lane], v1 = src[lane+64], v2 = src[lane+128];
    float s = v0+v1+v2;
    float q = v0*v0 + v1*v1 + v2*v2;
    #pragma unroll
    for (int m = 32; m; m >>= 1) { s += __shfl_xor(s, m, 64); q += __shfl_xor(q, m, 64); }
    float mu = s * (1.0f/CC);
    float inv = rsqrtf(fmaxf(q*(1.0f/CC) - mu*mu, 0.0f) + EPS_);
    dst[lane]     = __float2bfloat16((v0-mu)*inv*g[lane]     + bta[lane]);
    dst[lane+64]  = __float2bfloat16((v1-mu)*inv*g[lane+64]  + bta[lane+64]);
    dst[lane+128] = __float2bfloat16((v2-mu)*inv*g[lane+128] + bta[lane+128]);
}

// ---------------- K2: epipolar gather index map ----------------
__global__ __launch_bounds__(256) void map_kernel(
    const float* __restrict__ d_left, const float* __restrict__ d_right,
    int* __restrict__ map)
{
    int gid = blockIdx.x*256 + threadIdx.x;      // 0 .. 2*73728
    int side = (gid >= NSIDE_TOK) ? 1 : 0;
    int row = gid - side*NSIDE_TOK;
    int j = row % WIMG;
    float d = side ? d_right[row] : d_left[row];
    int jj;
    if (!side) { float f = (float)j + 0.5f - d; f = fmaxf(f, 0.f); jj = (int)f; }
    else       { float f = (float)j + 0.5f + d; f = fminf(f, 191.f); jj = (int)f; }
    map[gid] = (side ? 0 : NSIDE_TOK) + row - j + jj;
}

// ---------------- K3: convert weights to bf16 MFMA-FRAGMENT order ----------
__global__ __launch_bounds__(256) void conv_w_kernel(
    const float* __restrict__ q_w, const float* __restrict__ kv_w,
    const float* __restrict__ proj_w, const float* __restrict__ fc1_w,
    const float* __restrict__ fc2_w,
    __hip_bfloat16* __restrict__ q_wf, __hip_bfloat16* __restrict__ kv_wf,
    __hip_bfloat16* __restrict__ proj_f, __hip_bfloat16* __restrict__ W1f,
    __hip_bfloat16* __restrict__ W2f)
{
    int idx = blockIdx.x*256 + threadIdx.x;   // total 442368
    if (idx < 36864) {
        int j = idx & 7, lane = (idx>>3) & 63, fr = idx>>9;
        int ct = fr % 12, ks = fr / 12;
        int n = ct*16 + (lane&15), k = ks*32 + (lane>>4)*8 + j;
        q_wf[idx] = __float2bfloat16(q_w[(size_t)k*192 + n]);
    } else if (idx < 110592) {
        int i2 = idx - 36864;
        int j = i2 & 7, lane = (i2>>3) & 63, fr = i2>>9;
        int ct = fr % 24, ks = fr / 24;
        int n = ct*16 + (lane&15), k = ks*32 + (lane>>4)*8 + j;
        kv_wf[i2] = __float2bfloat16(kv_w[(size_t)k*384 + n]);
    } else if (idx < 147456) {
        int i2 = idx - 110592;
        int j = i2 & 7, lane = (i2>>3) & 63, fr = i2>>9;
        int ct = fr % 12, h = fr / 12;
        int n = ct*16 + (lane&15), k = h*32 + (lane>>4)*8 + j;
        proj_f[i2] = __float2bfloat16(proj_w[(size_t)k*192 + n]);
    } else if (idx < 294912) {
        // W1f: frag = (cc2*6 + ks)*2 + ct,  cc2 in [0,24), ct in [0,2)
        int i2 = idx - 147456;
        int j = i2 & 7, lane = (i2>>3) & 63, fr = i2>>9;
        int ct = fr & 1, ks = (fr>>1) % 6, cc2 = fr / 12;
        int n = cc2*32 + ct*16 + (lane&15), k = ks*32 + (lane>>4)*8 + j;
        W1f[i2] = __float2bfloat16(fc1_w[(size_t)k*MLPH + n]);
    } else {
        // W2f: frag = (cc*2+ks)*12+ct
        int i2 = idx - 294912;
        int j = i2 & 7, lane = (i2>>3) & 63, fr = i2>>9;
        int ct = fr % 12, ks = (fr/12) % 2, cc = fr / 24;
        int n = ct*16 + (lane&15), k = cc*64 + ks*32 + (lane>>4)*8 + j;
        W2f[i2] = __float2bfloat16(fc2_w[(size_t)k*192 + n]);
    }
}

// ---------------- K4: per-head rel-pos bias matrix [6][64][64] f32 ----------
__global__ __launch_bounds__(256) void bias_setup_kernel(
    const float* __restrict__ table, float* __restrict__ bias_glob)
{
    int idx = blockIdx.x*256 + threadIdx.x;   // 24576
    int h = idx >> 12, rem = idx & 4095;
    int q = rem >> 6, k = rem & 63;
    int qy = q>>3, qx = q&7, ky = k>>3, kx = k&7;
    int ridx = (qy-ky+7)*15 + (qx-kx+7);
    bias_glob[idx] = table[ridx*NHEADS + h];
}

// ---------------- K5: bf16 MFMA projection GEMM (A in regs, W staged in LDS)
template<int NT>
__global__ __launch_bounds__(256) void proj_gemm_kernel(
    const __hip_bfloat16* __restrict__ in, const __hip_bfloat16* __restrict__ Wf,
    const float* __restrict__ bias, const int* __restrict__ map,
    __hip_bfloat16* __restrict__ outp, float scale)
{
    __shared__ unsigned short wst[2][NT*512];
    const int tid = threadIdx.x, lane = tid & 63, w = tid >> 6;
    const int r16 = lane & 15, kg = lane >> 4, w16 = w*16;
    const size_t baserow = (size_t)blockIdx.x * 64;
    const int row = (int)baserow + w16 + r16;
    const size_t arow = map ? (size_t)map[row] : (size_t)row;

    bf16x8 aReg[6];
    #pragma unroll
    for (int ks = 0; ks < 6; ++ks)
        aReg[ks] = *reinterpret_cast<const bf16x8*>(in + arow*CC + ks*32 + kg*8);

    const char* wsrc = (const char*)Wf;
    const int soff = w*1024 + lane*16;
    #pragma unroll
    for (int i = 0; i < NT/4; ++i)
        gll16(wsrc + i*4096 + soff, (char*)wst[0] + i*4096 + w*1024);

    f32x4 acc[NT];
    #pragma unroll
    for (int ct = 0; ct < NT; ++ct) { float bv = bias[ct*16+r16]; acc[ct] = (f32x4){bv,bv,bv,bv}; }

    #pragma unroll
    for (int ks = 0; ks < 6; ++ks) {
        __syncthreads();
        if (ks < 5) {
            const char* s2 = wsrc + (size_t)(ks+1)*NT*1024;
            #pragma unroll
            for (int i = 0; i < NT/4; ++i)
                gll16(s2 + i*4096 + soff, (char*)wst[(ks+1)&1] + i*4096 + w*1024);
        }
        #pragma unroll
        for (int ct = 0; ct < NT; ++ct) {
            bf16x8 bb = *reinterpret_cast<const bf16x8*>(wst[ks&1] + ct*512 + lane*8);
            acc[ct] = __builtin_amdgcn_mfma_f32_16x16x32_bf16(aReg[ks], bb, acc[ct], 0, 0, 0);
        }
    }
    const int ldo = NT*16;
    #pragma unroll
    for (int ct = 0; ct < NT; ++ct)
        #pragma unroll
        for (int r = 0; r < 4; ++r)
            outp[(baserow + w16 + kg*4 + r)*ldo + ct*16 + r16] =
                __float2bfloat16(acc[ct][r] * scale);
}

// ---------------- K6: window attention + m, one barrier ---------------------
// grid 6912 = (window, head); 2 waves; wave s = side s. P kept in LDS (72
// stride) for both sides; one __syncthreads; m computed in-kernel reading P
// at native stride (8-way conflict on Pa reads, small phase). No repack (the
// round-9 in-place repack was a cross-lane LDS race).
__global__ __launch_bounds__(128) void attn_pm_kernel(
    const __hip_bfloat16* __restrict__ Qglob,   // [2][73728][192]
    const __hip_bfloat16* __restrict__ KVglob,  // [2][73728][384]
    const float* __restrict__ bias_glob,        // [6][64][64]
    __hip_bfloat16* __restrict__ Og,            // [2*1152*64][192]
    float* __restrict__ mg)                     // [2][1152][6][64]
{
    __shared__ unsigned short Pl[2][64*72];
    __shared__ unsigned short Vl[2][32*72];
    const int tid = threadIdx.x, lane = tid & 63, s = tid >> 6;
    const int r16 = lane & 15, kg = lane >> 4;
    const int bid = blockIdx.x;
    const int wd = bid / NHEADS, h = bid % NHEADS;
    const int b = wd / NWIN, win = wd % NWIN;
    const int wi = win / NWX, wj = win % NWX;
    const bool edge_i = (wi == NWX-1), edge_j = (wj == NWX-1);

    const __hip_bfloat16* Qs  = Qglob  + (size_t)s*NSIDE_TOK*CC;
    const __hip_bfloat16* KVs = KVglob + (size_t)s*NSIDE_TOK*(2*CC);

    int tokQ[4];
    #pragma unroll
    for (int mi = 0; mi < 4; ++mi) tokQ[mi] = tokof(b, wi, wj, mi*16 + r16);
    const int tokV = tokof(b, wi, wj, lane);

    unsigned short* P = Pl[s];
    unsigned short* V = Vl[s];

    // ---- stage V^T (wave-private)
    {
        bf16x8 vv[4];
        #pragma unroll
        for (int dg = 0; dg < 4; ++dg)
            vv[dg] = *reinterpret_cast<const bf16x8*>(
                KVs + (size_t)tokV*(2*CC) + CC + h*HD + dg*8);
        #pragma unroll
        for (int dg = 0; dg < 4; ++dg)
            #pragma unroll
            for (int jj = 0; jj < 8; ++jj)
                V[(dg*8+jj)*72 + lane] = (unsigned short)vv[dg][jj];
    }

    // ---- S = Q K^T
    bf16x8 aQ[4], bK[4];
    #pragma unroll
    for (int mi = 0; mi < 4; ++mi)
        aQ[mi] = *reinterpret_cast<const bf16x8*>(
            Qs + (size_t)tokQ[mi]*CC + h*HD + kg*8);
    #pragma unroll
    for (int ni = 0; ni < 4; ++ni)
        bK[ni] = *reinterpret_cast<const bf16x8*>(
            KVs + (size_t)tokQ[ni]*(2*CC) + h*HD + kg*8);
    f32x4 S[4][4];
    #pragma unroll
    for (int mi = 0; mi < 4; ++mi)
        #pragma unroll
        for (int ni = 0; ni < 4; ++ni)
            S[mi][ni] = __builtin_amdgcn_mfma_f32_16x16x32_bf16(
                aQ[mi], bK[ni], (f32x4){0.f,0.f,0.f,0.f}, 0, 0, 0);

    // ---- bias + shift mask
    #pragma unroll
    for (int mi = 0; mi < 4; ++mi)
        #pragma unroll
        for (int ni = 0; ni < 4; ++ni)
            #pragma unroll
            for (int rr = 0; rr < 4; ++rr) {
                int q = mi*16 + kg*4 + rr, k = ni*16 + r16;
                float bm = bias_glob[h*4096 + q*64 + k];
                int qy = q>>3, qx = q&7, ky = k>>3, kx = k&7;
                bool msk = (edge_i && ((qy<4) != (ky<4))) ||
                           (edge_j && ((qx<4) != (kx<4)));
                S[mi][ni][rr] += bm + (msk ? -100.0f : 0.0f);
            }

    // ---- softmax over k
    float mx[4][4], sm[4][4];
    #pragma unroll
    for (int mi = 0; mi < 4; ++mi)
        #pragma unroll
        for (int rr = 0; rr < 4; ++rr)
            mx[mi][rr] = fmaxf(fmaxf(S[mi][0][rr], S[mi][1][rr]),
                               fmaxf(S[mi][2][rr], S[mi][3][rr]));
    #pragma unroll
    for (int m = 1; m <= 8; m <<= 1)
        #pragma unroll
        for (int mi = 0; mi < 4; ++mi)
            #pragma unroll
            for (int rr = 0; rr < 4; ++rr)
                mx[mi][rr] = fmaxf(mx[mi][rr], __shfl_xor(mx[mi][rr], m, 64));
    #pragma unroll
    for (int mi = 0; mi < 4; ++mi)
        #pragma unroll
        for (int rr = 0; rr < 4; ++rr) sm[mi][rr] = 0.f;
    #pragma unroll
    for (int mi = 0; mi < 4; ++mi)
        #pragma unroll
        for (int ni = 0; ni < 4; ++ni)
            #pragma unroll
            for (int rr = 0; rr < 4; ++rr) {
                S[mi][ni][rr] = __expf(S[mi][ni][rr] - mx[mi][rr]);
                sm[mi][rr] += S[mi][ni][rr];
            }
    #pragma unroll
    for (int m = 1; m <= 8; m <<= 1)
        #pragma unroll
        for (int mi = 0; mi < 4; ++mi)
            #pragma unroll
            for (int rr = 0; rr < 4; ++rr)
                sm[mi][rr] += __shfl_xor(sm[mi][rr], m, 64);
    #pragma unroll
    for (int mi = 0; mi < 4; ++mi)
        #pragma unroll
        for (int rr = 0; rr < 4; ++rr) sm[mi][rr] = 1.0f / sm[mi][rr];

    // ---- P -> LDS (72-stride rows)
    #pragma unroll
    for (int mi = 0; mi < 4; ++mi)
        #pragma unroll
        for (int ni = 0; ni < 4; ++ni)
            #pragma unroll
            for (int rr = 0; rr < 4; ++rr)
                P[(mi*16 + kg*4 + rr)*72 + ni*16 + r16] =
                    f2bf(S[mi][ni][rr] * sm[mi][rr]);

    // ---- PV (own P, own V^T)
    {
        f32x4 O[4][2];
        #pragma unroll
        for (int mi = 0; mi < 4; ++mi)
            #pragma unroll
            for (int dt = 0; dt < 2; ++dt) O[mi][dt] = (f32x4){0.f,0.f,0.f,0.f};
        #pragma unroll
        for (int ks = 0; ks < 2; ++ks) {
            bf16x8 aP[4], bV[2];
            #pragma unroll
            for (int mi = 0; mi < 4; ++mi)
                aP[mi] = *reinterpret_cast<const bf16x8*>(
                    P + (mi*16 + r16)*72 + ks*32 + kg*8);
            #pragma unroll
            for (int dt = 0; dt < 2; ++dt)
                bV[dt] = *reinterpret_cast<const bf16x8*>(
                    V + (dt*16 + r16)*72 + ks*32 + kg*8);
            #pragma unroll
            for (int mi = 0; mi < 4; ++mi)
                #pragma unroll
                for (int dt = 0; dt < 2; ++dt)
                    O[mi][dt] = __builtin_amdgcn_mfma_f32_16x16x32_bf16(
                        aP[mi], bV[dt], O[mi][dt], 0, 0, 0);
        }
        __hip_bfloat16* ob = Og + ((size_t)(s*BWIN + wd)*64)*CC + h*HD;
        #pragma unroll
        for (int mi = 0; mi < 4; ++mi)
            #pragma unroll
            for (int dt = 0; dt < 2; ++dt)
                #pragma unroll
                for (int rr = 0; rr < 4; ++rr)
                    ob[(size_t)(mi*16 + kg*4 + rr)*CC + dt*16 + r16] =
                        __float2bfloat16(O[mi][dt][rr]);
    }

    __syncthreads();   // both waves' P visible

    // ---- m: wave s computes m for side s (P at native 72 stride)
    {
        const unsigned short* Pa = Pl[s];
        const unsigned short* Pb = Pl[s^1];
        const int i = lane;
        const int s0 = (i >= 2) ? -2 : -i;
        const int s1 = (i <= 61) ? 2 : 63 - i;
        float acc = 0.f;
        for (int k = 0; k < 64; k += 2) {
            float pb0 = bfu(Pb[k*72 + i]);
            float pb1 = bfu(Pb[(k+1)*72 + i]);
            float a0 = 0.f, a1 = 0.f;
            for (int ss = s0; ss <= s1; ++ss) {
                unsigned int pr = *reinterpret_cast<const unsigned int*>(
                    &Pa[(i+ss)*72 + k]);
                a0 += bfu((unsigned short)(pr & 0xffff));
                a1 += bfu((unsigned short)(pr >> 16));
            }
            acc += a0*pb0 + a1*pb1;
        }
        float e = __expf(10.0f * acc);           // tanh(5a), a >= 0
        mg[((size_t)(s*BWIN + wd)*NHEADS + h)*64 + i] = 1.0f - 2.0f/(e + 1.0f);
    }
}

// ---------------- K7: proj + fuse + reverse + residual + LN2 -> xln2 --------
__global__ __launch_bounds__(256) void projfuse_kernel(
    const __hip_bfloat16* __restrict__ Og,
    const __hip_bfloat16* __restrict__ proj_f,
    const float* __restrict__ proj_b,
    const float* __restrict__ mg,
    const __hip_bfloat16* __restrict__ xln_all,
    const float* __restrict__ x_left, const float* __restrict__ x_right,
    const float* __restrict__ g2, const float* __restrict__ b2,
    float* __restrict__ out, __hip_bfloat16* __restrict__ xln2)
{
    __shared__ unsigned short wst[2][12*512];
    const int tid = threadIdx.x, lane = tid & 63, w = tid >> 6;
    const int r16 = lane & 15, kg = lane >> 4, w16 = w*16;
    const int bid = blockIdx.x;
    const int s = bid / BWIN, wd = bid % BWIN;
    const int b = wd / NWIN, win = wd % NWIN;
    const int wi = win / NWX, wj = win % NWX;

    const size_t orow = (size_t)(s*BWIN + wd)*64 + w16 + r16;
    bf16x8 aReg[6];
    #pragma unroll
    for (int ks = 0; ks < 6; ++ks)
        aReg[ks] = *reinterpret_cast<const bf16x8*>(Og + orow*CC + ks*32 + kg*8);

    const char* wsrc = (const char*)proj_f;
    const int soff = w*1024 + lane*16;
    #pragma unroll
    for (int i = 0; i < 3; ++i)
        gll16(wsrc + i*4096 + soff, (char*)wst[0] + i*4096 + w*1024);

    f32x4 acc[12];
    #pragma unroll
    for (int ct = 0; ct < 12; ++ct) { float bv = proj_b[ct*16+r16]; acc[ct] = (f32x4){bv,bv,bv,bv}; }

    #pragma unroll
    for (int ks = 0; ks < 6; ++ks) {
        __syncthreads();
        if (ks < 5) {
            const char* s2 = wsrc + (size_t)(ks+1)*12288;
            #pragma unroll
            for (int i = 0; i < 3; ++i)
                gll16(s2 + i*4096 + soff, (char*)wst[(ks+1)&1] + i*4096 + w*1024);
        }
        #pragma unroll
        for (int ct = 0; ct < 12; ++ct) {
            bf16x8 bb = *reinterpret_cast<const bf16x8*>(wst[ks&1] + ct*512 + lane*8);
            acc[ct] = __builtin_amdgcn_mfma_f32_16x16x32_bf16(aReg[ks], bb, acc[ct], 0, 0, 0);
        }
    }

    // ---- epilogue: fuse + window reverse + residual (keep values in acc)
    int tk[4];
    #pragma unroll
    for (int rr = 0; rr < 4; ++rr) tk[rr] = tokof(b, wi, wj, w16 + kg*4 + rr);
    const float* xo_s = s ? x_right : x_left;
    const __hip_bfloat16* xw_s = xln_all + (size_t)s*NSIDE_TOK*CC;
    float* out_s = out + (size_t)s*NSIDE_TOK*CC;
    __hip_bfloat16* xln2_s = xln2 + (size_t)s*NSIDE_TOK*CC;
    const float* mrow = mg + (size_t)(s*BWIN + wd)*NHEADS*64;

    float g2c[12], b2c[12];
    #pragma unroll
    for (int ct = 0; ct < 12; ++ct) {
        g2c[ct] = g2[ct*16 + r16];
        b2c[ct] = b2[ct*16 + r16];
    }

    #pragma unroll
    for (int ct = 0; ct < 12; ++ct) {
        int col = ct*16 + r16;
        int h = ct >> 1;
        #pragma unroll
        for (int rr = 0; rr < 4; ++rr) {
            int q = w16 + kg*4 + rr;
            size_t tt = (size_t)tk[rr];
            float m = mrow[h*64 + q];
            float xw = __bfloat162float(xw_s[tt*CC + col]);
            float p = acc[ct][rr];
            float val = xo_s[tt*CC + col] + xw + (p - xw)*m;
            out_s[tt*CC + col] = val;
            acc[ct][rr] = val;
        }
    }

    // ---- LN2 of fused output -> bf16 xln2 (stats via 16-lane shuffles)
    #pragma unroll
    for (int rr = 0; rr < 4; ++rr) {
        float sum = 0.f, sq = 0.f;
        #pragma unroll
        for (int ct = 0; ct < 12; ++ct) {
            float v = acc[ct][rr];
            sum += v; sq += v*v;
        }
        #pragma unroll
        for (int m = 1; m <= 8; m <<= 1) {
            sum += __shfl_xor(sum, m, 64);
            sq  += __shfl_xor(sq,  m, 64);
        }
        float mu = sum * (1.0f/CC);
        float inv = rsqrtf(fmaxf(sq*(1.0f/CC) - mu*mu, 0.0f) + EPS_);
        size_t tt = (size_t)tk[rr];
        #pragma unroll
        for (int ct = 0; ct < 12; ++ct) {
            unsigned short uv = f2bf((acc[ct][rr]-mu)*inv*g2c[ct] + b2c[ct]);
            *reinterpret_cast<unsigned short*>(&xln2_s[tt*CC + ct*16 + r16]) = uv;
        }
    }
}

// ---------------- K8: fused MLP (LN2 precomputed; A from xln2 global) -------
__global__ __launch_bounds__(256) void mlp_mfma_kernel(
    float* __restrict__ out, const __hip_bfloat16* __restrict__ xln2,
    const __hip_bfloat16* __restrict__ W1f, const float* __restrict__ fc1_b,
    const __hip_bfloat16* __restrict__ W2f, const float* __restrict__ fc2_b)
{
    __shared__ unsigned short hbuf[64*72];    // 9216 B (wave-private rows)
    __shared__ unsigned short wst[2][6144];   // 2 x 12288 B weight staging
    const int tid  = threadIdx.x;
    const int lane = tid & 63;
    const int w    = tid >> 6;
    const int r16 = lane & 15, kg = lane >> 4, w16 = w*16;
    const size_t base = (size_t)blockIdx.x * 64 * CC;

    bf16x8 aReg[6];
    #pragma unroll
    for (int ks = 0; ks < 6; ++ks)
        aReg[ks] = *reinterpret_cast<const bf16x8*>(
            xln2 + base + (size_t)(w16 + r16)*CC + ks*32 + kg*8);

    const char* W1c = (const char*)W1f;
    const char* W2c = (const char*)W2f;
    const int soff = w*1024 + lane*16;
    const int doff = w*1024;

    #pragma unroll
    for (int i = 0; i < 3; ++i)
        gll16(W1c + i*4096 + soff, (char*)wst[0] + i*4096 + doff);

    f32x4 acc2[12];
    #pragma unroll
    for (int i = 0; i < 12; ++i) acc2[i] = (f32x4){0.f,0.f,0.f,0.f};

    for (int cc = 0; cc < 12; ++cc) {
        f32x4 acc1[4];
        __syncthreads();
        {
            const char* s2 = W1c + (size_t)(2*cc+1)*12288;
            #pragma unroll
            for (int i = 0; i < 3; ++i)
                gll16(s2 + i*4096 + soff, (char*)wst[1] + i*4096 + doff);
        }
        #pragma unroll
        for (int c2 = 0; c2 < 2; ++c2) {
            float bv = fc1_b[cc*64 + c2*16 + r16];
            acc1[c2] = (f32x4){bv,bv,bv,bv};
        }
        #pragma unroll
        for (int ks = 0; ks < 6; ++ks)
            #pragma unroll
            for (int c2 = 0; c2 < 2; ++c2) {
                bf16x8 bw = *reinterpret_cast<const bf16x8*>(wst[0] + (ks*2+c2)*512 + lane*8);
                acc1[c2] = __builtin_amdgcn_mfma_f32_16x16x32_bf16(aReg[ks], bw, acc1[c2], 0, 0, 0);
            }
        __syncthreads();
        {
            const char* s2 = W2c + (size_t)(2*cc)*12288;
            #pragma unroll
            for (int i = 0; i < 3; ++i)
                gll16(s2 + i*4096 + soff, (char*)wst[0] + i*4096 + doff);
        }
        #pragma unroll
        for (int c2 = 0; c2 < 2; ++c2) {
            float bv = fc1_b[cc*64 + 32 + c2*16 + r16];
            acc1[2+c2] = (f32x4){bv,bv,bv,bv};
        }
        #pragma unroll
        for (int ks = 0; ks < 6; ++ks)
            #pragma unroll
            for (int c2 = 0; c2 < 2; ++c2) {
                bf16x8 bw = *reinterpret_cast<const bf16x8*>(wst[1] + (ks*2+c2)*512 + lane*8);
                acc1[2+c2] = __builtin_amdgcn_mfma_f32_16x16x32_bf16(aReg[ks], bw, acc1[2+c2], 0, 0, 0);
            }
        #pragma unroll
        for (int ct = 0; ct < 4; ++ct)
            #pragma unroll
            for (int r = 0; r < 4; ++r)
                hbuf[(w16 + kg*4 + r)*72 + ct*16 + r16] = f2bf(gelu_fast(acc1[ct][r]));
        __syncthreads();
        {
            const char* s2 = W2c + (size_t)(2*cc+1)*12288;
            #pragma unroll
            for (int i = 0; i < 3; ++i)
                gll16(s2 + i*4096 + soff, (char*)wst[1] + i*4096 + doff);
        }
        {
            bf16x8 aP = *reinterpret_cast<const bf16x8*>(hbuf + (w16+r16)*72 + kg*8);
            #pragma unroll
            for (int ct = 0; ct < 12; ++ct) {
                bf16x8 bw = *reinterpret_cast<const bf16x8*>(wst[0] + ct*512 + lane*8);
                acc2[ct] = __builtin_amdgcn_mfma_f32_16x16x32_bf16(aP, bw, acc2[ct], 0, 0, 0);
            }
        }
        __syncthreads();
        if (cc < 11) {
            const char* s2 = W1c + (size_t)(2*cc+2)*12288;
            #pragma unroll
            for (int i = 0; i < 3; ++i)
                gll16(s2 + i*4096 + soff, (char*)wst[0] + i*4096 + doff);
        }
        {
            bf16x8 aP = *reinterpret_cast<const bf16x8*>(hbuf + (w16+r16)*72 + 32 + kg*8);
            #pragma unroll
            for (int ct = 0; ct < 12; ++ct) {
                bf16x8 bw = *reinterpret_cast<const bf16x8*>(wst[1] + ct*512 + lane*8);
                acc2[ct] = __builtin_amdgcn_mfma_f32_16x16x32_bf16(aP, bw, acc2[ct], 0, 0, 0);
            }
        }
    }

    #pragma unroll
    for (int ct = 0; ct < 12; ++ct) {
        int col = ct*16 + r16;
        float bv = fc2_b[col];
        #pragma unroll
        for (int r = 0; r < 4; ++r) {
            size_t idx = base + (size_t)(w16 + kg*4 + r)*CC + col;
            out[idx] = out[idx] + acc2[ct][r] + bv;
        }
    }
}

// ---------------- launch ----------------
extern "C" void kernel_launch(void* const* d_in, const int* in_sizes, int n_in,
                              void* d_out, int out_size, void* d_ws, size_t ws_size,
                              hipStream_t stream)
{
    (void)in_sizes; (void)n_in; (void)out_size; (void)ws_size;
    const float* x_left  = (const float*)d_in[0];
    const float* x_right = (const float*)d_in[1];
    const float* d_left  = (const float*)d_in[2];
    const float* d_right = (const float*)d_in[3];
    const float* n1g = (const float*)d_in[4];
    const float* n1b = (const float*)d_in[5];
    const float* q_w = (const float*)d_in[6];
    const float* q_b = (const float*)d_in[7];
    const float* kv_w = (const float*)d_in[8];
    const float* kv_b = (const float*)d_in[9];
    const float* proj_w = (const float*)d_in[10];
    const float* proj_b = (const float*)d_in[11];
    const float* bias_table = (const float*)d_in[12];
    const float* n2g = (const float*)d_in[13];
    const float* n2b = (const float*)d_in[14];
    const float* fc1_w = (const float*)d_in[15];
    const float* fc1_b = (const float*)d_in[16];
    const float* fc2_w = (const float*)d_in[17];
    const float* fc2_b = (const float*)d_in[18];
    float* out = (float*)d_out;

    char* ws = (char*)d_ws;
    __hip_bfloat16* xln_all  = (__hip_bfloat16*)(ws);                 // 56623104 B
    __hip_bfloat16* Qg       = (__hip_bfloat16*)(ws + 56623104);      // 56623104 B
    __hip_bfloat16* KVg      = (__hip_bfloat16*)(ws + 113246208);     // 113246208 B
    __hip_bfloat16* xln2     = (__hip_bfloat16*)(ws + 113246208);     // aliases KVg (dead after attn)
    __hip_bfloat16* q_wf     = (__hip_bfloat16*)(ws + 226492416);     // 73728 B
    __hip_bfloat16* kv_wf    = (__hip_bfloat16*)(ws + 226566144);     // 147456 B
    __hip_bfloat16* proj_f   = (__hip_bfloat16*)(ws + 226713600);     // 73728 B
    __hip_bfloat16* W1f      = (__hip_bfloat16*)(ws + 226787328);     // 294912 B
    __hip_bfloat16* W2f      = (__hip_bfloat16*)(ws + 227082240);     // 294912 B
    float*          bias_g   = (float*)         (ws + 227377152);     // 393216 B
    __hip_bfloat16* Og       = (__hip_bfloat16*)(ws + 227770368);     // 56623104 B
    int*            map      = (int*)           (ws + 284393472);     // 589824 B
    float*          mg       = (float*)         (ws + 284983296);     // 3538944 B

    ln1_kernel<<<(2*NSIDE_TOK)/4, 256, 0, stream>>>(x_left, x_right, n1g, n1b, xln_all);

    conv_w_kernel<<<1728, 256, 0, stream>>>(q_w, kv_w, proj_w, fc1_w, fc2_w,
                                            q_wf, kv_wf, proj_f, W1f, W2f);
    bias_setup_kernel<<<96, 256, 0, stream>>>(bias_table, bias_g);
    map_kernel<<<(2*NSIDE_TOK)/256, 256, 0, stream>>>(d_left, d_right, map);

    // KV = gather(xln) @ kv_w + kv_b  (A gathered through map)
    proj_gemm_kernel<24><<<(2*NSIDE_TOK)/64, 256, 0, stream>>>(
        xln_all, kv_wf, kv_b, map, KVg, 1.0f);
    // Q = (xln @ q_w + q_b) * scale
    proj_gemm_kernel<12><<<(2*NSIDE_TOK)/64, 256, 0, stream>>>(
        xln_all, q_wf, q_b, nullptr, Qg, 0.17677669529663687f);

    attn_pm_kernel<<<BWIN*NHEADS, 128, 0, stream>>>(Qg, KVg, bias_g, Og, mg);

    projfuse_kernel<<<2*BWIN, 256, 0, stream>>>(
        Og, proj_f, proj_b, mg, xln_all, x_left, x_right, n2g, n2b, out, xln2);

    mlp_mfma_kernel<<<(2*NSIDE_TOK)/64, 256, 0, stream>>>(
        out, xln2, W1f, fc1_b, W2f, fc2_b);
}